// Round 17
// baseline (259.960 us; speedup 1.0000x reference)
//
#include <hip/hip_runtime.h>

// ---------------------------------------------------------------------------
// AttentionHead: B=4, C=256, N=4096, QK=64. Column-softmax attention.
// R29 = R28 (the 196.2us anchor) + k_attn at 2 blocks/CU:
//  i-block 64->32, grid 256->512 (b=id&3 pin kept), 1024 thr / 16 waves,
//  wave = 16-c strip (cstrip = wid), m-loops halved, P dbuf 33.8KB ->
//  2 blocks/CU = 32 waves/CU, __launch_bounds__(1024,8).
// Rationale: the {32 waves/CU x coalesced-V} cell was never tested. R16's
// failure at 32 waves predated frag-major (R19) and was caused by doubled
// SCATTERED V gathers (~6cyc/line TA serialization) - now coalesced 1KB
// bursts, doubling costs only L2 BW (~1GB @ 34TB/s aggregate). k_attn
// counters (Mfma 23, VALU 24, LDS ~40%, HBM 10%, Occ 40) = latency-bound,
// exactly what TLP doubling addresses. Stagger/dbuf/V-hoist/cvt_pk/setprio/
// rs-fold preserved; fused MLP on 32-row tile (R24-verified mapping, halved
// ranges). k_prep/k_proj/k_colsum byte-identical to R28.
// ---------------------------------------------------------------------------

typedef unsigned short u16;
typedef __attribute__((ext_vector_type(8))) unsigned short ushort8;
typedef __attribute__((ext_vector_type(2))) unsigned int uint2v;
typedef __attribute__((ext_vector_type(8))) __bf16 bf16x8;
typedef __attribute__((ext_vector_type(4))) float f32x4;

#define MFMA16(a, b, c) __builtin_amdgcn_mfma_f32_16x16x32_bf16((a), (b), (c), 0, 0, 0)

__device__ __forceinline__ u16 f2bf(float f) {
  unsigned int u = __builtin_bit_cast(unsigned int, f);
  u += 0x7FFFu + ((u >> 16) & 1u);  // round-to-nearest-even
  return (u16)(u >> 16);
}

__device__ __forceinline__ float bf2f(u16 v) {
  return __builtin_bit_cast(float, (unsigned int)v << 16);
}

__device__ __forceinline__ unsigned int cvtpk(float lo, float hi) {
  unsigned int r;
  asm("v_cvt_pk_bf16_f32 %0, %1, %2" : "=v"(r) : "v"(lo), "v"(hi));
  return r;
}

__device__ __forceinline__ bf16x8 ld8(const u16* p) {
  return __builtin_bit_cast(bf16x8, *reinterpret_cast<const ushort8*>(p));
}

__device__ __forceinline__ f32x4 fz4() {
  f32x4 z = {0.f, 0.f, 0.f, 0.f};
  return z;
}

// Fragment-major addressing (u16 units):
//  frag block fb = strip*NK + kchunk; addr = (fb<<9) + lane*8 + e
//  lane = idx15 + 16*g holds tensor[idx = strip*16 + idx15][k = kchunk*32 + g*8 + e]
//  Qf/Kf per batch: 256 istrips x 2 dchunks (NK=2); xTf: 256 x 8 (NK=8)
//  Vf per batch: 16 cstrips x 128 jchunks (NK=128); weights: O/16 x 8 (NK=8)

// ---- fused prep: transpose (blocks 0..1023) + weight convert (1024..1135) -
__global__ __launch_bounds__(256) void k_prep(
    const float* __restrict__ x, const float* __restrict__ wq,
    const float* __restrict__ wk, const float* __restrict__ wv,
    const float* __restrict__ w1, const float* __restrict__ w2,
    u16* __restrict__ xT, u16* __restrict__ dq, u16* __restrict__ dk,
    u16* __restrict__ dv, u16* __restrict__ d1, u16* __restrict__ d2) {
  __shared__ float t[64][65];
  int id = blockIdx.x;
  if (id < 1024) {
    int n0 = (id & 63) * 64, c0 = ((id >> 6) & 3) * 64, b = id >> 8;
    int tx = threadIdx.x & 63, ty = threadIdx.x >> 6;
    const float* xb = x + ((size_t)b * 256 + c0) * 4096 + n0;
#pragma unroll
    for (int i = 0; i < 64; i += 4) t[ty + i][tx] = xb[(size_t)(ty + i) * 4096 + tx];
    __syncthreads();
    int lane = tx, w = ty;
    int l15 = lane & 15, g = lane >> 4;
    u16* xob = xT + (size_t)b * 1048576;
    int nstrip = (n0 >> 4) + w;
#pragma unroll
    for (int q = 0; q < 2; ++q) {
      int kk = (c0 >> 5) + q;
      int cl = q * 32 + g * 8;
      ushort8 v;
#pragma unroll
      for (int e = 0; e < 8; ++e) v[e] = f2bf(t[cl + e][w * 16 + l15]);
      *reinterpret_cast<ushort8*>(xob + ((size_t)(nstrip * 8 + kk) << 9) + lane * 8) = v;
    }
  } else {
    int tt = (id - 1024) * 256 + threadIdx.x;
    int lane = tt & 63, fb = tt >> 6;  // 448 frag blocks total
    const float* src;
    u16* dst;
    int base;
    if (fb < 32)       { src = wq; dst = dq; base = 0; }
    else if (fb < 64)  { src = wk; dst = dk; base = 32; }
    else if (fb < 192) { src = wv; dst = dv; base = 64; }
    else if (fb < 320) { src = w1; dst = d1; base = 192; }
    else               { src = w2; dst = d2; base = 320; }
    int lfb = fb - base;
    int ostrip = lfb >> 3, kk = lfb & 7;
    int l15 = lane & 15, g = lane >> 4;
    const float* s = src + (ostrip * 16 + l15) * 256 + kk * 32 + g * 8;
    f32x4 a0 = *reinterpret_cast<const f32x4*>(s);
    f32x4 a1 = *reinterpret_cast<const f32x4*>(s + 4);
    ushort8 v;
#pragma unroll
    for (int e = 0; e < 4; ++e) { v[e] = f2bf(a0[e]); v[4 + e] = f2bf(a1[e]); }
    *reinterpret_cast<ushort8*>(dst + ((size_t)lfb << 9) + lane * 8) = v;
  }
}

// ---- fused QKV projection: 32-pos tiles, grid 512 linear (b = id&3) -------
__global__ __launch_bounds__(256) void k_proj(
    const u16* __restrict__ xT, const u16* __restrict__ wq,
    const u16* __restrict__ wk, const u16* __restrict__ wv,
    const float* __restrict__ bQ, const float* __restrict__ bK,
    const float* __restrict__ bV, const float* __restrict__ PE,
    u16* __restrict__ Qt, u16* __restrict__ Kt, u16* __restrict__ Vc) {
  int b = blockIdx.x & 3, n0 = (blockIdx.x >> 2) * 32;
  int lane = threadIdx.x & 63, wid = threadIdx.x >> 6;
  int l15 = lane & 15, g = lane >> 4;
  const u16* xf = xT + (size_t)b * 1048576;

  f32x4 aq[2], ak[2], av[4][2];
#pragma unroll
  for (int m = 0; m < 2; ++m) { aq[m] = fz4(); ak[m] = fz4(); }
#pragma unroll
  for (int m = 0; m < 4; ++m)
#pragma unroll
    for (int n = 0; n < 2; ++n) av[m][n] = fz4();

  for (int kk = 0; kk < 8; ++kk) {
    bf16x8 xa[2];
#pragma unroll
    for (int m = 0; m < 2; ++m)
      xa[m] = ld8(xf + ((((n0 >> 4) + m) * 8 + kk) << 9) + lane * 8);
    bf16x8 fq = ld8(wq + ((wid * 8 + kk) << 9) + lane * 8);
    bf16x8 fk = ld8(wk + ((wid * 8 + kk) << 9) + lane * 8);
#pragma unroll
    for (int m = 0; m < 2; ++m) {
      aq[m] = MFMA16(xa[m], fq, aq[m]);
      ak[m] = MFMA16(xa[m], fk, ak[m]);
    }
    bf16x8 fv[4];
#pragma unroll
    for (int m = 0; m < 4; ++m)
      fv[m] = ld8(wv + (((4 * wid + m) * 8 + kk) << 9) + lane * 8);
#pragma unroll
    for (int m = 0; m < 4; ++m)
#pragma unroll
      for (int n = 0; n < 2; ++n) av[m][n] = MFMA16(fv[m], xa[n], av[m][n]);
  }

  // Q/K fragment writes: o = 16*wid+l15 (col), pos = n0+16m+4g+r (row)
  int o = 16 * wid + l15;
  int dc = wid >> 1;                      // o>>5
  int gp = (16 * (wid & 1) + l15) >> 3;   // (o&31)>>3
  int eo = l15 & 7;                       // o&7
  u16* qf = Qt + (size_t)b * 262144;
  u16* kf = Kt + (size_t)b * 262144;
#pragma unroll
  for (int m = 0; m < 2; ++m) {
    int istrip = (n0 >> 4) + m;
    f32x4 pe4 = *reinterpret_cast<const f32x4*>(PE + o * 4096 + n0 + 16 * m + 4 * g);
#pragma unroll
    for (int r = 0; r < 4; ++r) {
      size_t a = (size_t)(((istrip * 2 + dc) << 9) + ((4 * g + r) + 16 * gp) * 8 + eo);
      qf[a] = f2bf(aq[m][r] + bQ[o] + pe4[r]);
      kf[a] = f2bf(ak[m][r] + bK[o] + pe4[r]);
    }
  }
  // V fragment writes: c = 64wid+16m+4g+r (row idx), pos = n0+16n+l15 (col k)
  u16* vf = Vc + (size_t)b * 1048576;
  int jchunk = n0 >> 5;
#pragma unroll
  for (int m = 0; m < 4; ++m) {
    int cstrip = 4 * wid + m;
#pragma unroll
    for (int r = 0; r < 4; ++r) {
      int c15 = 4 * g + r;
      float bvv = bV[64 * wid + 16 * m + c15];
#pragma unroll
      for (int n = 0; n < 2; ++n) {
        size_t a = (size_t)(((cstrip * 128 + jchunk) << 9) +
                            (c15 + 16 * (2 * n + (l15 >> 3))) * 8 + (l15 & 7));
        vf[a] = f2bf(av[m][n][r] + bvv);
      }
    }
  }
}

// ---- pass 1: column sums + fold 1/colsum into Vf, 512 thr, grid 256 -------
__global__ __launch_bounds__(512) void k_colsum(const u16* __restrict__ Qt,
                                                const u16* __restrict__ Kt,
                                                u16* __restrict__ Vc) {
  __shared__ float ps[8][16];
  __shared__ float rsf[64];
  int b = blockIdx.x & 3, j0 = (blockIdx.x >> 2) * 64;
  int lane = threadIdx.x & 63, wid = threadIdx.x >> 6;  // wid in [0,8)
  int l15 = lane & 15, g = lane >> 4;
  int w4 = wid & 3, ihalf = wid >> 2;
  const u16* qf = Qt + (size_t)b * 262144;
  const u16* kf = Kt + (size_t)b * 262144;
  int jstrip = (j0 >> 4) + w4;
  bf16x8 fk[2];
#pragma unroll
  for (int h = 0; h < 2; ++h)
    fk[h] = ld8(kf + ((jstrip * 2 + h) << 9) + lane * 8);
  float part = 0.f;
  for (int i0 = ihalf * 2048; i0 < ihalf * 2048 + 2048; i0 += 64) {
    f32x4 acc[4];
#pragma unroll
    for (int m = 0; m < 4; ++m) acc[m] = fz4();
#pragma unroll
    for (int m = 0; m < 4; ++m) {
      int ib = ((i0 >> 4) + m) * 2;
      acc[m] = MFMA16(ld8(qf + (ib << 9) + lane * 8), fk[0], acc[m]);
      acc[m] = MFMA16(ld8(qf + ((ib + 1) << 9) + lane * 8), fk[1], acc[m]);
    }
#pragma unroll
    for (int m = 0; m < 4; ++m)
#pragma unroll
      for (int r = 0; r < 4; ++r) part += __expf(acc[m][r] * 0.125f);
  }
  part += __shfl_xor(part, 16);
  part += __shfl_xor(part, 32);
  if (g == 0) ps[wid][l15] = part;
  __syncthreads();
  if (threadIdx.x < 64) {
    int jj = threadIdx.x;
    rsf[jj] = 1.0f / (ps[jj >> 4][jj & 15] + ps[(jj >> 4) + 4][jj & 15]);
  }
  __syncthreads();
  // scale Vf for j in [j0, j0+64), all 256 channels (2 threads / channel)
  {
    int c = threadIdx.x >> 1, half = threadIdx.x & 1;
    int cstrip = c >> 4, c15 = c & 15;
    u16* vb2 = Vc + (size_t)b * 1048576;
#pragma unroll
    for (int q = 0; q < 2; ++q) {
      int jo = half * 32 + q * 16;
#pragma unroll
      for (int s = 0; s < 2; ++s) {
        int joo = jo + s * 8;
        int jc = (j0 + joo) >> 5;
        int jg = (joo & 31) >> 3;
        u16* p = vb2 + (((size_t)(cstrip * 128 + jc)) << 9) + (c15 + 16 * jg) * 8;
        ushort8 v = *reinterpret_cast<const ushort8*>(p);
        ushort8 ov;
#pragma unroll
        for (int e = 0; e < 8; ++e) ov[e] = f2bf(bf2f(v[e]) * rsf[joo + e]);
        *reinterpret_cast<ushort8*>(p) = ov;
      }
    }
  }
}

// ---- pass 2: attention + fused MLP, 1024 thr, grid 512 (b = id&3) ---------
// 32-i blocks, 2 blocks/CU (32 waves). Wave = 16-c strip (cstrip = wid).
// Stagger + dbuf + V-hoist + cvt_pk + setprio + rs-fold preserved; MLP on
// the 32-row tile (R24-verified mapping, m/n ranges halved).
__global__ __launch_bounds__(1024, 8) void k_attn(
    const u16* __restrict__ Qt, const u16* __restrict__ Kt,
    const u16* __restrict__ Vc, const u16* __restrict__ w1,
    const float* __restrict__ b1, const u16* __restrict__ w2,
    const float* __restrict__ b2, const float* __restrict__ x,
    float* __restrict__ out) {
  __shared__ u16 P[2][32][264];  // dbuf; reused as att/hdn tiles for MLP
  int b = blockIdx.x & 3, i0 = (blockIdx.x >> 2) * 32;
  int lane = threadIdx.x & 63, wid = threadIdx.x >> 6;  // wid in [0,16)
  int l15 = lane & 15, g = lane >> 4;
  const u16* qf = Qt + (size_t)b * 262144;
  const u16* kf = Kt + (size_t)b * 262144;
  const u16* vf = Vc + (size_t)b * 1048576;

  bf16x8 aq[2][2];  // block's 32 Q rows (istrips i0/16, i0/16+1)
#pragma unroll
  for (int m = 0; m < 2; ++m)
#pragma unroll
    for (int h = 0; h < 2; ++h)
      aq[m][h] = ld8(qf + ((((i0 >> 4) + m) * 2 + h) << 9) + lane * 8);

  f32x4 oacc[2];  // [m]: i = i0+16m+4g+r, c = 16*wid+l15
#pragma unroll
  for (int m = 0; m < 2; ++m) oacc[m] = fz4();

  const u16* kl = kf + lane * 8;
  bf16x8 fk0 = ld8(kl + ((wid * 2 + 0) << 9));
  bf16x8 fk1 = ld8(kl + ((wid * 2 + 1) << 9));

  auto S_phase = [&](int j0, int sbuf) {
    f32x4 s[2];
#pragma unroll
    for (int m = 0; m < 2; ++m) {
      s[m] = fz4();
      s[m] = MFMA16(fk0, aq[m][0], s[m]);
      s[m] = MFMA16(fk1, aq[m][1], s[m]);
    }
#pragma unroll
    for (int m = 0; m < 2; ++m) {
      float e0 = __expf(s[m][0] * 0.125f);
      float e1 = __expf(s[m][1] * 0.125f);
      float e2 = __expf(s[m][2] * 0.125f);
      float e3 = __expf(s[m][3] * 0.125f);
      uint2v w = {cvtpk(e0, e1), cvtpk(e2, e3)};
      *reinterpret_cast<uint2v*>(&P[sbuf][16 * m + l15][16 * wid + 4 * g]) = w;
    }
    if (j0 < 3840) {
      int jstrip = ((j0 + 256) >> 4) + wid;
      fk0 = ld8(kl + ((jstrip * 2 + 0) << 9));
      fk1 = ld8(kl + ((jstrip * 2 + 1) << 9));
    }
  };
  auto PV_phase = [&](int j0, int pbuf, const bf16x8 (&fvp)[4]) {
    __builtin_amdgcn_s_setprio(1);
#pragma unroll
    for (int h = 0; h < 8; ++h) {
      bf16x8 ap[2];
#pragma unroll
      for (int m = 0; m < 2; ++m)
        ap[m] = ld8(&P[pbuf][16 * m + l15][h * 32 + 8 * g]);
      bf16x8 f0;
      if (h < 4) {
        f0 = fvp[h];
      } else {
        f0 = ld8(vf + (((wid) * 128 + (j0 >> 5) + h) << 9) + lane * 8);
      }
      oacc[0] = MFMA16(ap[0], f0, oacc[0]);
      oacc[1] = MFMA16(ap[1], f0, oacc[1]);
    }
    __builtin_amdgcn_s_setprio(0);
  };

  S_phase(0, 0);
  int buf = 0;
  for (int t = 0; t < 16; ++t) {
    __syncthreads();
    int j0 = t * 256;
    bf16x8 fvp[4];
#pragma unroll
    for (int h = 0; h < 4; ++h)
      fvp[h] = ld8(vf + (((wid) * 128 + (j0 >> 5) + h) << 9) + lane * 8);
    if (wid & 1) {
      if (t < 15) S_phase(j0 + 256, buf ^ 1);
      PV_phase(j0, buf, fvp);
    } else {
      PV_phase(j0, buf, fvp);
      if (t < 15) S_phase(j0 + 256, buf ^ 1);
    }
    buf ^= 1;
  }

  // ---- fused MLP on the block's 32x256 tile ----
  u16 (*attL)[264] = P[0];  // att tile (P dead after j-loop)
  u16 (*hdnL)[264] = P[1];  // hdn tile
  __syncthreads();  // all PV reads of P complete
#pragma unroll
  for (int m = 0; m < 2; ++m)
#pragma unroll
    for (int r = 0; r < 4; ++r)
      attL[16 * m + 4 * g + r][16 * wid + l15] = f2bf(oacc[m][r]);
  __syncthreads();

  // stage 1: hdn = mish(att @ W1^T + b1); wave strip = 16 h (ostrip = wid)
  {
    f32x4 acc1[2];
#pragma unroll
    for (int m = 0; m < 2; ++m) acc1[m] = fz4();
    for (int kk = 0; kk < 8; ++kk) {
      bf16x8 bn = ld8(w1 + ((wid * 8 + kk) << 9) + lane * 8);
#pragma unroll
      for (int m = 0; m < 2; ++m) {
        bf16x8 am = ld8(&attL[16 * m + l15][kk * 32 + 8 * g]);
        acc1[m] = MFMA16(am, bn, acc1[m]);
      }
    }
    float bb = b1[16 * wid + l15];
#pragma unroll
    for (int m = 0; m < 2; ++m)
#pragma unroll
      for (int r = 0; r < 4; ++r) {
        float v = acc1[m][r] + bb;
        float sp = (v > 15.f) ? v : __logf(1.f + __expf(v));
        float e2 = __expf(-2.f * sp);
        float th = (1.f - e2) / (1.f + e2);
        hdnL[16 * m + 4 * g + r][16 * wid + l15] = f2bf(v * th);
      }
  }
  __syncthreads();

  // stage 2: out = hdn @ W2^T + b2 + x; wave strip = 16 o (ostrip = wid)
  {
    f32x4 acc2[2];
#pragma unroll
    for (int n = 0; n < 2; ++n) acc2[n] = fz4();
    for (int kk = 0; kk < 8; ++kk) {
      bf16x8 am = ld8(w2 + ((wid * 8 + kk) << 9) + lane * 8);
#pragma unroll
      for (int n = 0; n < 2; ++n) {
        bf16x8 bn = ld8(&hdnL[16 * n + l15][kk * 32 + 8 * g]);
        acc2[n] = MFMA16(am, bn, acc2[n]);
      }
    }
    f32x4 b2v = *reinterpret_cast<const f32x4*>(b2 + 16 * wid + 4 * g);
#pragma unroll
    for (int r = 0; r < 4; ++r) {
      int o = 16 * wid + 4 * g + r;
#pragma unroll
      for (int n = 0; n < 2; ++n) {
        int pos = i0 + 16 * n + l15;
        size_t idx = ((size_t)b * 256 + o) * 4096 + pos;
        out[idx] = acc2[n][r] + b2v[r] + x[idx];
      }
    }
  }
}

// ---- workspace layout (bytes) ---------------------------------------------
#define WS_XT 0u          //  8,388,608  xTf  [4][256*8][64][8] bf16
#define WS_QT 8388608u    //  2,097,152  Qf  [4][256*2][64][8] bf16
#define WS_KT 10485760u   //  2,097,152  Kf  [4][256*2][64][8] bf16
#define WS_VC 12582912u   //  8,388,608  Vf  [4][16*128][64][8] bf16
#define WS_WQ 21037056u   //     32,768  wqf [4*8][64][8]
#define WS_WK 21069824u   //     32,768
#define WS_WV 21102592u   //    131,072  wvf [16*8][64][8]
#define WS_W1 21233664u   //    131,072
#define WS_W2 21364736u   //    131,072   (end: 21,495,808 < 29,884,416)

extern "C" void kernel_launch(void* const* d_in, const int* in_sizes, int n_in,
                              void* d_out, int out_size, void* d_ws, size_t ws_size,
                              hipStream_t stream) {
  (void)in_sizes; (void)n_in; (void)out_size; (void)ws_size;
  const float* x  = (const float*)d_in[0];
  const float* WQ = (const float*)d_in[1];
  const float* bQ = (const float*)d_in[2];
  const float* WK = (const float*)d_in[3];
  const float* bK = (const float*)d_in[4];
  const float* WV = (const float*)d_in[5];
  const float* bV = (const float*)d_in[6];
  const float* PE = (const float*)d_in[7];
  const float* W1 = (const float*)d_in[8];
  const float* b1 = (const float*)d_in[9];
  const float* W2 = (const float*)d_in[10];
  const float* b2 = (const float*)d_in[11];
  float* out = (float*)d_out;
  char* ws = (char*)d_ws;

  u16* xT   = (u16*)(ws + WS_XT);
  u16* Qt   = (u16*)(ws + WS_QT);
  u16* Kt   = (u16*)(ws + WS_KT);
  u16* Vc   = (u16*)(ws + WS_VC);
  u16* wqB  = (u16*)(ws + WS_WQ);
  u16* wkB  = (u16*)(ws + WS_WK);
  u16* wvB  = (u16*)(ws + WS_WV);
  u16* w1B  = (u16*)(ws + WS_W1);
  u16* w2B  = (u16*)(ws + WS_W2);

  k_prep<<<1136, 256, 0, stream>>>(x, WQ, WK, WV, W1, W2, xT, wqB, wkB, wvB, w1B, w2B);
  k_proj<<<512, 256, 0, stream>>>(xT, wqB, wkB, wvB, bQ, bK, bV, PE, Qt, Kt, Vc);
  k_colsum<<<256, 512, 0, stream>>>(Qt, Kt, Vc);
  k_attn<<<512, 1024, 0, stream>>>(Qt, Kt, Vc, w1B, b1, w2B, b2, x, out);
}

// Round 18
// 237.097 us; speedup vs baseline: 1.0964x; 1.0964x over previous
//
#include <hip/hip_runtime.h>

// ---------------------------------------------------------------------------
// AttentionHead: B=4, C=256, N=4096, QK=64. Column-softmax attention.
// R30 = R29 with the SPILL removed. R29's failure was a confound:VGPR_Count
// 32 (launch_bounds(1024,8) cap) -> scratch spill -> WRITE 166MB / FETCH
// 118MB of spill traffic. Fix: drop the V-hoist (fvp, -16 VGPR; T14 is null
// at high TLP) so the kernel fits 64 VGPR without spilling. All else = R29:
// 32-i blocks, grid 512 (b=id&3), 1024 thr / 16 waves (wave = 16-c strip),
// P dbuf 33.8KB -> 2 blocks/CU = 32 waves/CU. R28's 1 block/CU was imposed
// by grid=256 alone (LDS 67.6KB and VGPR 64 both allow 2 blocks).
// Falsifiable: VGPR 48-64, WRITE ~35MB, FETCH ~50MB, Occ ~72%; k_attn
// 55-70us if latency-bound, else plateau confirmed -> revert R28 next.
// k_prep/k_proj/k_colsum byte-identical to R28/R29.
// ---------------------------------------------------------------------------

typedef unsigned short u16;
typedef __attribute__((ext_vector_type(8))) unsigned short ushort8;
typedef __attribute__((ext_vector_type(2))) unsigned int uint2v;
typedef __attribute__((ext_vector_type(8))) __bf16 bf16x8;
typedef __attribute__((ext_vector_type(4))) float f32x4;

#define MFMA16(a, b, c) __builtin_amdgcn_mfma_f32_16x16x32_bf16((a), (b), (c), 0, 0, 0)

__device__ __forceinline__ u16 f2bf(float f) {
  unsigned int u = __builtin_bit_cast(unsigned int, f);
  u += 0x7FFFu + ((u >> 16) & 1u);  // round-to-nearest-even
  return (u16)(u >> 16);
}

__device__ __forceinline__ float bf2f(u16 v) {
  return __builtin_bit_cast(float, (unsigned int)v << 16);
}

__device__ __forceinline__ unsigned int cvtpk(float lo, float hi) {
  unsigned int r;
  asm("v_cvt_pk_bf16_f32 %0, %1, %2" : "=v"(r) : "v"(lo), "v"(hi));
  return r;
}

__device__ __forceinline__ bf16x8 ld8(const u16* p) {
  return __builtin_bit_cast(bf16x8, *reinterpret_cast<const ushort8*>(p));
}

__device__ __forceinline__ f32x4 fz4() {
  f32x4 z = {0.f, 0.f, 0.f, 0.f};
  return z;
}

// Fragment-major addressing (u16 units):
//  frag block fb = strip*NK + kchunk; addr = (fb<<9) + lane*8 + e
//  lane = idx15 + 16*g holds tensor[idx = strip*16 + idx15][k = kchunk*32 + g*8 + e]
//  Qf/Kf per batch: 256 istrips x 2 dchunks (NK=2); xTf: 256 x 8 (NK=8)
//  Vf per batch: 16 cstrips x 128 jchunks (NK=128); weights: O/16 x 8 (NK=8)

// ---- fused prep: transpose (blocks 0..1023) + weight convert (1024..1135) -
__global__ __launch_bounds__(256) void k_prep(
    const float* __restrict__ x, const float* __restrict__ wq,
    const float* __restrict__ wk, const float* __restrict__ wv,
    const float* __restrict__ w1, const float* __restrict__ w2,
    u16* __restrict__ xT, u16* __restrict__ dq, u16* __restrict__ dk,
    u16* __restrict__ dv, u16* __restrict__ d1, u16* __restrict__ d2) {
  __shared__ float t[64][65];
  int id = blockIdx.x;
  if (id < 1024) {
    int n0 = (id & 63) * 64, c0 = ((id >> 6) & 3) * 64, b = id >> 8;
    int tx = threadIdx.x & 63, ty = threadIdx.x >> 6;
    const float* xb = x + ((size_t)b * 256 + c0) * 4096 + n0;
#pragma unroll
    for (int i = 0; i < 64; i += 4) t[ty + i][tx] = xb[(size_t)(ty + i) * 4096 + tx];
    __syncthreads();
    int lane = tx, w = ty;
    int l15 = lane & 15, g = lane >> 4;
    u16* xob = xT + (size_t)b * 1048576;
    int nstrip = (n0 >> 4) + w;
#pragma unroll
    for (int q = 0; q < 2; ++q) {
      int kk = (c0 >> 5) + q;
      int cl = q * 32 + g * 8;
      ushort8 v;
#pragma unroll
      for (int e = 0; e < 8; ++e) v[e] = f2bf(t[cl + e][w * 16 + l15]);
      *reinterpret_cast<ushort8*>(xob + ((size_t)(nstrip * 8 + kk) << 9) + lane * 8) = v;
    }
  } else {
    int tt = (id - 1024) * 256 + threadIdx.x;
    int lane = tt & 63, fb = tt >> 6;  // 448 frag blocks total
    const float* src;
    u16* dst;
    int base;
    if (fb < 32)       { src = wq; dst = dq; base = 0; }
    else if (fb < 64)  { src = wk; dst = dk; base = 32; }
    else if (fb < 192) { src = wv; dst = dv; base = 64; }
    else if (fb < 320) { src = w1; dst = d1; base = 192; }
    else               { src = w2; dst = d2; base = 320; }
    int lfb = fb - base;
    int ostrip = lfb >> 3, kk = lfb & 7;
    int l15 = lane & 15, g = lane >> 4;
    const float* s = src + (ostrip * 16 + l15) * 256 + kk * 32 + g * 8;
    f32x4 a0 = *reinterpret_cast<const f32x4*>(s);
    f32x4 a1 = *reinterpret_cast<const f32x4*>(s + 4);
    ushort8 v;
#pragma unroll
    for (int e = 0; e < 4; ++e) { v[e] = f2bf(a0[e]); v[4 + e] = f2bf(a1[e]); }
    *reinterpret_cast<ushort8*>(dst + ((size_t)lfb << 9) + lane * 8) = v;
  }
}

// ---- fused QKV projection: 32-pos tiles, grid 512 linear (b = id&3) -------
__global__ __launch_bounds__(256) void k_proj(
    const u16* __restrict__ xT, const u16* __restrict__ wq,
    const u16* __restrict__ wk, const u16* __restrict__ wv,
    const float* __restrict__ bQ, const float* __restrict__ bK,
    const float* __restrict__ bV, const float* __restrict__ PE,
    u16* __restrict__ Qt, u16* __restrict__ Kt, u16* __restrict__ Vc) {
  int b = blockIdx.x & 3, n0 = (blockIdx.x >> 2) * 32;
  int lane = threadIdx.x & 63, wid = threadIdx.x >> 6;
  int l15 = lane & 15, g = lane >> 4;
  const u16* xf = xT + (size_t)b * 1048576;

  f32x4 aq[2], ak[2], av[4][2];
#pragma unroll
  for (int m = 0; m < 2; ++m) { aq[m] = fz4(); ak[m] = fz4(); }
#pragma unroll
  for (int m = 0; m < 4; ++m)
#pragma unroll
    for (int n = 0; n < 2; ++n) av[m][n] = fz4();

  for (int kk = 0; kk < 8; ++kk) {
    bf16x8 xa[2];
#pragma unroll
    for (int m = 0; m < 2; ++m)
      xa[m] = ld8(xf + ((((n0 >> 4) + m) * 8 + kk) << 9) + lane * 8);
    bf16x8 fq = ld8(wq + ((wid * 8 + kk) << 9) + lane * 8);
    bf16x8 fk = ld8(wk + ((wid * 8 + kk) << 9) + lane * 8);
#pragma unroll
    for (int m = 0; m < 2; ++m) {
      aq[m] = MFMA16(xa[m], fq, aq[m]);
      ak[m] = MFMA16(xa[m], fk, ak[m]);
    }
    bf16x8 fv[4];
#pragma unroll
    for (int m = 0; m < 4; ++m)
      fv[m] = ld8(wv + (((4 * wid + m) * 8 + kk) << 9) + lane * 8);
#pragma unroll
    for (int m = 0; m < 4; ++m)
#pragma unroll
      for (int n = 0; n < 2; ++n) av[m][n] = MFMA16(fv[m], xa[n], av[m][n]);
  }

  // Q/K fragment writes: o = 16*wid+l15 (col), pos = n0+16m+4g+r (row)
  int o = 16 * wid + l15;
  int dc = wid >> 1;                      // o>>5
  int gp = (16 * (wid & 1) + l15) >> 3;   // (o&31)>>3
  int eo = l15 & 7;                       // o&7
  u16* qf = Qt + (size_t)b * 262144;
  u16* kf = Kt + (size_t)b * 262144;
#pragma unroll
  for (int m = 0; m < 2; ++m) {
    int istrip = (n0 >> 4) + m;
    f32x4 pe4 = *reinterpret_cast<const f32x4*>(PE + o * 4096 + n0 + 16 * m + 4 * g);
#pragma unroll
    for (int r = 0; r < 4; ++r) {
      size_t a = (size_t)(((istrip * 2 + dc) << 9) + ((4 * g + r) + 16 * gp) * 8 + eo);
      qf[a] = f2bf(aq[m][r] + bQ[o] + pe4[r]);
      kf[a] = f2bf(ak[m][r] + bK[o] + pe4[r]);
    }
  }
  // V fragment writes: c = 64wid+16m+4g+r (row idx), pos = n0+16n+l15 (col k)
  u16* vf = Vc + (size_t)b * 1048576;
  int jchunk = n0 >> 5;
#pragma unroll
  for (int m = 0; m < 4; ++m) {
    int cstrip = 4 * wid + m;
#pragma unroll
    for (int r = 0; r < 4; ++r) {
      int c15 = 4 * g + r;
      float bvv = bV[64 * wid + 16 * m + c15];
#pragma unroll
      for (int n = 0; n < 2; ++n) {
        size_t a = (size_t)(((cstrip * 128 + jchunk) << 9) +
                            (c15 + 16 * (2 * n + (l15 >> 3))) * 8 + (l15 & 7));
        vf[a] = f2bf(av[m][n][r] + bvv);
      }
    }
  }
}

// ---- pass 1: column sums + fold 1/colsum into Vf, 512 thr, grid 256 -------
__global__ __launch_bounds__(512) void k_colsum(const u16* __restrict__ Qt,
                                                const u16* __restrict__ Kt,
                                                u16* __restrict__ Vc) {
  __shared__ float ps[8][16];
  __shared__ float rsf[64];
  int b = blockIdx.x & 3, j0 = (blockIdx.x >> 2) * 64;
  int lane = threadIdx.x & 63, wid = threadIdx.x >> 6;  // wid in [0,8)
  int l15 = lane & 15, g = lane >> 4;
  int w4 = wid & 3, ihalf = wid >> 2;
  const u16* qf = Qt + (size_t)b * 262144;
  const u16* kf = Kt + (size_t)b * 262144;
  int jstrip = (j0 >> 4) + w4;
  bf16x8 fk[2];
#pragma unroll
  for (int h = 0; h < 2; ++h)
    fk[h] = ld8(kf + ((jstrip * 2 + h) << 9) + lane * 8);
  float part = 0.f;
  for (int i0 = ihalf * 2048; i0 < ihalf * 2048 + 2048; i0 += 64) {
    f32x4 acc[4];
#pragma unroll
    for (int m = 0; m < 4; ++m) acc[m] = fz4();
#pragma unroll
    for (int m = 0; m < 4; ++m) {
      int ib = ((i0 >> 4) + m) * 2;
      acc[m] = MFMA16(ld8(qf + (ib << 9) + lane * 8), fk[0], acc[m]);
      acc[m] = MFMA16(ld8(qf + ((ib + 1) << 9) + lane * 8), fk[1], acc[m]);
    }
#pragma unroll
    for (int m = 0; m < 4; ++m)
#pragma unroll
      for (int r = 0; r < 4; ++r) part += __expf(acc[m][r] * 0.125f);
  }
  part += __shfl_xor(part, 16);
  part += __shfl_xor(part, 32);
  if (g == 0) ps[wid][l15] = part;
  __syncthreads();
  if (threadIdx.x < 64) {
    int jj = threadIdx.x;
    rsf[jj] = 1.0f / (ps[jj >> 4][jj & 15] + ps[(jj >> 4) + 4][jj & 15]);
  }
  __syncthreads();
  // scale Vf for j in [j0, j0+64), all 256 channels (2 threads / channel)
  {
    int c = threadIdx.x >> 1, half = threadIdx.x & 1;
    int cstrip = c >> 4, c15 = c & 15;
    u16* vb2 = Vc + (size_t)b * 1048576;
#pragma unroll
    for (int q = 0; q < 2; ++q) {
      int jo = half * 32 + q * 16;
#pragma unroll
      for (int s = 0; s < 2; ++s) {
        int joo = jo + s * 8;
        int jc = (j0 + joo) >> 5;
        int jg = (joo & 31) >> 3;
        u16* p = vb2 + (((size_t)(cstrip * 128 + jc)) << 9) + (c15 + 16 * jg) * 8;
        ushort8 v = *reinterpret_cast<const ushort8*>(p);
        ushort8 ov;
#pragma unroll
        for (int e = 0; e < 8; ++e) ov[e] = f2bf(bf2f(v[e]) * rsf[joo + e]);
        *reinterpret_cast<ushort8*>(p) = ov;
      }
    }
  }
}

// ---- pass 2: attention + fused MLP, 1024 thr, grid 512 (b = id&3) ---------
// 32-i blocks, 2 blocks/CU (32 waves). Wave = 16-c strip (cstrip = wid).
// No V-hoist (register budget: must fit 64 VGPR at 8 waves/SIMD, no spill).
__global__ __launch_bounds__(1024, 8) void k_attn(
    const u16* __restrict__ Qt, const u16* __restrict__ Kt,
    const u16* __restrict__ Vc, const u16* __restrict__ w1,
    const float* __restrict__ b1, const u16* __restrict__ w2,
    const float* __restrict__ b2, const float* __restrict__ x,
    float* __restrict__ out) {
  __shared__ u16 P[2][32][264];  // dbuf; reused as att/hdn tiles for MLP
  int b = blockIdx.x & 3, i0 = (blockIdx.x >> 2) * 32;
  int lane = threadIdx.x & 63, wid = threadIdx.x >> 6;  // wid in [0,16)
  int l15 = lane & 15, g = lane >> 4;
  const u16* qf = Qt + (size_t)b * 262144;
  const u16* kf = Kt + (size_t)b * 262144;
  const u16* vf = Vc + (size_t)b * 1048576;

  bf16x8 aq[2][2];  // block's 32 Q rows (istrips i0/16, i0/16+1)
#pragma unroll
  for (int m = 0; m < 2; ++m)
#pragma unroll
    for (int h = 0; h < 2; ++h)
      aq[m][h] = ld8(qf + ((((i0 >> 4) + m) * 2 + h) << 9) + lane * 8);

  f32x4 oacc[2];  // [m]: i = i0+16m+4g+r, c = 16*wid+l15
#pragma unroll
  for (int m = 0; m < 2; ++m) oacc[m] = fz4();

  const u16* kl = kf + lane * 8;
  bf16x8 fk0 = ld8(kl + ((wid * 2 + 0) << 9));
  bf16x8 fk1 = ld8(kl + ((wid * 2 + 1) << 9));

  auto S_phase = [&](int j0, int sbuf) {
    f32x4 s[2];
#pragma unroll
    for (int m = 0; m < 2; ++m) {
      s[m] = fz4();
      s[m] = MFMA16(fk0, aq[m][0], s[m]);
      s[m] = MFMA16(fk1, aq[m][1], s[m]);
    }
#pragma unroll
    for (int m = 0; m < 2; ++m) {
      float e0 = __expf(s[m][0] * 0.125f);
      float e1 = __expf(s[m][1] * 0.125f);
      float e2 = __expf(s[m][2] * 0.125f);
      float e3 = __expf(s[m][3] * 0.125f);
      uint2v w = {cvtpk(e0, e1), cvtpk(e2, e3)};
      *reinterpret_cast<uint2v*>(&P[sbuf][16 * m + l15][16 * wid + 4 * g]) = w;
    }
    if (j0 < 3840) {
      int jstrip = ((j0 + 256) >> 4) + wid;
      fk0 = ld8(kl + ((jstrip * 2 + 0) << 9));
      fk1 = ld8(kl + ((jstrip * 2 + 1) << 9));
    }
  };
  auto PV_phase = [&](int j0, int pbuf) {
    __builtin_amdgcn_s_setprio(1);
#pragma unroll
    for (int h = 0; h < 8; ++h) {
      bf16x8 ap[2];
#pragma unroll
      for (int m = 0; m < 2; ++m)
        ap[m] = ld8(&P[pbuf][16 * m + l15][h * 32 + 8 * g]);
      bf16x8 f0 = ld8(vf + ((wid * 128 + (j0 >> 5) + h) << 9) + lane * 8);
      oacc[0] = MFMA16(ap[0], f0, oacc[0]);
      oacc[1] = MFMA16(ap[1], f0, oacc[1]);
    }
    __builtin_amdgcn_s_setprio(0);
  };

  S_phase(0, 0);
  int buf = 0;
  for (int t = 0; t < 16; ++t) {
    __syncthreads();
    int j0 = t * 256;
    if (wid & 1) {
      if (t < 15) S_phase(j0 + 256, buf ^ 1);
      PV_phase(j0, buf);
    } else {
      PV_phase(j0, buf);
      if (t < 15) S_phase(j0 + 256, buf ^ 1);
    }
    buf ^= 1;
  }

  // ---- fused MLP on the block's 32x256 tile ----
  u16 (*attL)[264] = P[0];  // att tile (P dead after j-loop)
  u16 (*hdnL)[264] = P[1];  // hdn tile
  __syncthreads();  // all PV reads of P complete
#pragma unroll
  for (int m = 0; m < 2; ++m)
#pragma unroll
    for (int r = 0; r < 4; ++r)
      attL[16 * m + 4 * g + r][16 * wid + l15] = f2bf(oacc[m][r]);
  __syncthreads();

  // stage 1: hdn = mish(att @ W1^T + b1); wave strip = 16 h (ostrip = wid)
  {
    f32x4 acc1[2];
#pragma unroll
    for (int m = 0; m < 2; ++m) acc1[m] = fz4();
    for (int kk = 0; kk < 8; ++kk) {
      bf16x8 bn = ld8(w1 + ((wid * 8 + kk) << 9) + lane * 8);
#pragma unroll
      for (int m = 0; m < 2; ++m) {
        bf16x8 am = ld8(&attL[16 * m + l15][kk * 32 + 8 * g]);
        acc1[m] = MFMA16(am, bn, acc1[m]);
      }
    }
    float bb = b1[16 * wid + l15];
#pragma unroll
    for (int m = 0; m < 2; ++m)
#pragma unroll
      for (int r = 0; r < 4; ++r) {
        float v = acc1[m][r] + bb;
        float sp = (v > 15.f) ? v : __logf(1.f + __expf(v));
        float e2 = __expf(-2.f * sp);
        float th = (1.f - e2) / (1.f + e2);
        hdnL[16 * m + 4 * g + r][16 * wid + l15] = f2bf(v * th);
      }
  }
  __syncthreads();

  // stage 2: out = hdn @ W2^T + b2 + x; wave strip = 16 o (ostrip = wid)
  {
    f32x4 acc2[2];
#pragma unroll
    for (int n = 0; n < 2; ++n) acc2[n] = fz4();
    for (int kk = 0; kk < 8; ++kk) {
      bf16x8 am = ld8(w2 + ((wid * 8 + kk) << 9) + lane * 8);
#pragma unroll
      for (int n = 0; n < 2; ++n) {
        bf16x8 bn = ld8(&hdnL[16 * n + l15][kk * 32 + 8 * g]);
        acc2[n] = MFMA16(am, bn, acc2[n]);
      }
    }
    f32x4 b2v = *reinterpret_cast<const f32x4*>(b2 + 16 * wid + 4 * g);
#pragma unroll
    for (int r = 0; r < 4; ++r) {
      int o = 16 * wid + 4 * g + r;
#pragma unroll
      for (int n = 0; n < 2; ++n) {
        int pos = i0 + 16 * n + l15;
        size_t idx = ((size_t)b * 256 + o) * 4096 + pos;
        out[idx] = acc2[n][r] + b2v[r] + x[idx];
      }
    }
  }
}

// ---- workspace layout (bytes) ---------------------------------------------
#define WS_XT 0u          //  8,388,608  xTf  [4][256*8][64][8] bf16
#define WS_QT 8388608u    //  2,097,152  Qf  [4][256*2][64][8] bf16
#define WS_KT 10485760u   //  2,097,152  Kf  [4][256*2][64][8] bf16
#define WS_VC 12582912u   //  8,388,608  Vf  [4][16*128][64][8] bf16
#define WS_WQ 21037056u   //     32,768  wqf [4*8][64][8]
#define WS_WK 21069824u   //     32,768
#define WS_WV 21102592u   //    131,072  wvf [16*8][64][8]
#define WS_W1 21233664u   //    131,072
#define WS_W2 21364736u   //    131,072   (end: 21,495,808 < 29,884,416)

extern "C" void kernel_launch(void* const* d_in, const int* in_sizes, int n_in,
                              void* d_out, int out_size, void* d_ws, size_t ws_size,
                              hipStream_t stream) {
  (void)in_sizes; (void)n_in; (void)out_size; (void)ws_size;
  const float* x  = (const float*)d_in[0];
  const float* WQ = (const float*)d_in[1];
  const float* bQ = (const float*)d_in[2];
  const float* WK = (const float*)d_in[3];
  const float* bK = (const float*)d_in[4];
  const float* WV = (const float*)d_in[5];
  const float* bV = (const float*)d_in[6];
  const float* PE = (const float*)d_in[7];
  const float* W1 = (const float*)d_in[8];
  const float* b1 = (const float*)d_in[9];
  const float* W2 = (const float*)d_in[10];
  const float* b2 = (const float*)d_in[11];
  float* out = (float*)d_out;
  char* ws = (char*)d_ws;

  u16* xT   = (u16*)(ws + WS_XT);
  u16* Qt   = (u16*)(ws + WS_QT);
  u16* Kt   = (u16*)(ws + WS_KT);
  u16* Vc   = (u16*)(ws + WS_VC);
  u16* wqB  = (u16*)(ws + WS_WQ);
  u16* wkB  = (u16*)(ws + WS_WK);
  u16* wvB  = (u16*)(ws + WS_WV);
  u16* w1B  = (u16*)(ws + WS_W1);
  u16* w2B  = (u16*)(ws + WS_W2);

  k_prep<<<1136, 256, 0, stream>>>(x, WQ, WK, WV, W1, W2, xT, wqB, wkB, wvB, w1B, w2B);
  k_proj<<<512, 256, 0, stream>>>(xT, wqB, wkB, wvB, bQ, bK, bV, PE, Qt, Kt, Vc);
  k_colsum<<<256, 512, 0, stream>>>(Qt, Kt, Vc);
  k_attn<<<512, 1024, 0, stream>>>(Qt, Kt, Vc, w1B, b1, w2B, b2, x, out);
}

// Round 19
// 197.447 us; speedup vs baseline: 1.3166x; 1.2008x over previous
//
#include <hip/hip_runtime.h>

// ---------------------------------------------------------------------------
// AttentionHead: B=4, C=256, N=4096, QK=64. Column-softmax attention.
// R31 = R28 VERBATIM (best harness-verified: 196.2us). Final configuration.
// Closed axes (with counter evidence):
//  - 32 waves/CU for fused attn+MLP: infeasible. gfx950 unified VGPR/AGPR
//    file -> 8 waves/SIMD = 64 unified regs/wave; kernel needs ~96 (R29/R30:
//    compiler allocates 32 arch + spills, WRITE 151-166MB scratch traffic).
//  - Launch-gap/ramp overhead: refuted by R27 (coop fusion; grid.sync
//    ~100us+ at 256x1024 across 8 XCDs -> 515us).
//  - Occupancy on prep kernels (R25), transpose-pass elimination (R26):
//    neutral -> non-attn time is distributed real work.
// Session wins: R19 frag-major coalescing (-62us; ~6cyc/line TA gather
// serialization mechanism), R21 stagger (-4), R24 MLP+prep fusion (-13),
// R17 pad (-3). 284.8 -> 196.2us.
// ---------------------------------------------------------------------------

typedef unsigned short u16;
typedef __attribute__((ext_vector_type(8))) unsigned short ushort8;
typedef __attribute__((ext_vector_type(2))) unsigned int uint2v;
typedef __attribute__((ext_vector_type(8))) __bf16 bf16x8;
typedef __attribute__((ext_vector_type(4))) float f32x4;

#define MFMA16(a, b, c) __builtin_amdgcn_mfma_f32_16x16x32_bf16((a), (b), (c), 0, 0, 0)

__device__ __forceinline__ u16 f2bf(float f) {
  unsigned int u = __builtin_bit_cast(unsigned int, f);
  u += 0x7FFFu + ((u >> 16) & 1u);  // round-to-nearest-even
  return (u16)(u >> 16);
}

__device__ __forceinline__ float bf2f(u16 v) {
  return __builtin_bit_cast(float, (unsigned int)v << 16);
}

__device__ __forceinline__ unsigned int cvtpk(float lo, float hi) {
  unsigned int r;
  asm("v_cvt_pk_bf16_f32 %0, %1, %2" : "=v"(r) : "v"(lo), "v"(hi));
  return r;
}

__device__ __forceinline__ bf16x8 ld8(const u16* p) {
  return __builtin_bit_cast(bf16x8, *reinterpret_cast<const ushort8*>(p));
}

__device__ __forceinline__ f32x4 fz4() {
  f32x4 z = {0.f, 0.f, 0.f, 0.f};
  return z;
}

// Fragment-major addressing (u16 units):
//  frag block fb = strip*NK + kchunk; addr = (fb<<9) + lane*8 + e
//  lane = idx15 + 16*g holds tensor[idx = strip*16 + idx15][k = kchunk*32 + g*8 + e]
//  Qf/Kf per batch: 256 istrips x 2 dchunks (NK=2); xTf: 256 x 8 (NK=8)
//  Vf per batch: 16 cstrips x 128 jchunks (NK=128); weights: O/16 x 8 (NK=8)

// ---- fused prep: transpose (blocks 0..1023) + weight convert (1024..1135) -
__global__ __launch_bounds__(256) void k_prep(
    const float* __restrict__ x, const float* __restrict__ wq,
    const float* __restrict__ wk, const float* __restrict__ wv,
    const float* __restrict__ w1, const float* __restrict__ w2,
    u16* __restrict__ xT, u16* __restrict__ dq, u16* __restrict__ dk,
    u16* __restrict__ dv, u16* __restrict__ d1, u16* __restrict__ d2) {
  __shared__ float t[64][65];
  int id = blockIdx.x;
  if (id < 1024) {
    int n0 = (id & 63) * 64, c0 = ((id >> 6) & 3) * 64, b = id >> 8;
    int tx = threadIdx.x & 63, ty = threadIdx.x >> 6;
    const float* xb = x + ((size_t)b * 256 + c0) * 4096 + n0;
#pragma unroll
    for (int i = 0; i < 64; i += 4) t[ty + i][tx] = xb[(size_t)(ty + i) * 4096 + tx];
    __syncthreads();
    int lane = tx, w = ty;
    int l15 = lane & 15, g = lane >> 4;
    u16* xob = xT + (size_t)b * 1048576;
    int nstrip = (n0 >> 4) + w;
#pragma unroll
    for (int q = 0; q < 2; ++q) {
      int kk = (c0 >> 5) + q;
      int cl = q * 32 + g * 8;
      ushort8 v;
#pragma unroll
      for (int e = 0; e < 8; ++e) v[e] = f2bf(t[cl + e][w * 16 + l15]);
      *reinterpret_cast<ushort8*>(xob + ((size_t)(nstrip * 8 + kk) << 9) + lane * 8) = v;
    }
  } else {
    int tt = (id - 1024) * 256 + threadIdx.x;
    int lane = tt & 63, fb = tt >> 6;  // 448 frag blocks total
    const float* src;
    u16* dst;
    int base;
    if (fb < 32)       { src = wq; dst = dq; base = 0; }
    else if (fb < 64)  { src = wk; dst = dk; base = 32; }
    else if (fb < 192) { src = wv; dst = dv; base = 64; }
    else if (fb < 320) { src = w1; dst = d1; base = 192; }
    else               { src = w2; dst = d2; base = 320; }
    int lfb = fb - base;
    int ostrip = lfb >> 3, kk = lfb & 7;
    int l15 = lane & 15, g = lane >> 4;
    const float* s = src + (ostrip * 16 + l15) * 256 + kk * 32 + g * 8;
    f32x4 a0 = *reinterpret_cast<const f32x4*>(s);
    f32x4 a1 = *reinterpret_cast<const f32x4*>(s + 4);
    ushort8 v;
#pragma unroll
    for (int e = 0; e < 4; ++e) { v[e] = f2bf(a0[e]); v[4 + e] = f2bf(a1[e]); }
    *reinterpret_cast<ushort8*>(dst + ((size_t)lfb << 9) + lane * 8) = v;
  }
}

// ---- fused QKV projection: 32-pos tiles, grid 512 linear (b = id&3) -------
__global__ __launch_bounds__(256) void k_proj(
    const u16* __restrict__ xT, const u16* __restrict__ wq,
    const u16* __restrict__ wk, const u16* __restrict__ wv,
    const float* __restrict__ bQ, const float* __restrict__ bK,
    const float* __restrict__ bV, const float* __restrict__ PE,
    u16* __restrict__ Qt, u16* __restrict__ Kt, u16* __restrict__ Vc) {
  int b = blockIdx.x & 3, n0 = (blockIdx.x >> 2) * 32;
  int lane = threadIdx.x & 63, wid = threadIdx.x >> 6;
  int l15 = lane & 15, g = lane >> 4;
  const u16* xf = xT + (size_t)b * 1048576;

  f32x4 aq[2], ak[2], av[4][2];
#pragma unroll
  for (int m = 0; m < 2; ++m) { aq[m] = fz4(); ak[m] = fz4(); }
#pragma unroll
  for (int m = 0; m < 4; ++m)
#pragma unroll
    for (int n = 0; n < 2; ++n) av[m][n] = fz4();

  for (int kk = 0; kk < 8; ++kk) {
    bf16x8 xa[2];
#pragma unroll
    for (int m = 0; m < 2; ++m)
      xa[m] = ld8(xf + ((((n0 >> 4) + m) * 8 + kk) << 9) + lane * 8);
    bf16x8 fq = ld8(wq + ((wid * 8 + kk) << 9) + lane * 8);
    bf16x8 fk = ld8(wk + ((wid * 8 + kk) << 9) + lane * 8);
#pragma unroll
    for (int m = 0; m < 2; ++m) {
      aq[m] = MFMA16(xa[m], fq, aq[m]);
      ak[m] = MFMA16(xa[m], fk, ak[m]);
    }
    bf16x8 fv[4];
#pragma unroll
    for (int m = 0; m < 4; ++m)
      fv[m] = ld8(wv + (((4 * wid + m) * 8 + kk) << 9) + lane * 8);
#pragma unroll
    for (int m = 0; m < 4; ++m)
#pragma unroll
      for (int n = 0; n < 2; ++n) av[m][n] = MFMA16(fv[m], xa[n], av[m][n]);
  }

  // Q/K fragment writes: o = 16*wid+l15 (col), pos = n0+16m+4g+r (row)
  int o = 16 * wid + l15;
  int dc = wid >> 1;                      // o>>5
  int gp = (16 * (wid & 1) + l15) >> 3;   // (o&31)>>3
  int eo = l15 & 7;                       // o&7
  u16* qf = Qt + (size_t)b * 262144;
  u16* kf = Kt + (size_t)b * 262144;
#pragma unroll
  for (int m = 0; m < 2; ++m) {
    int istrip = (n0 >> 4) + m;
    f32x4 pe4 = *reinterpret_cast<const f32x4*>(PE + o * 4096 + n0 + 16 * m + 4 * g);
#pragma unroll
    for (int r = 0; r < 4; ++r) {
      size_t a = (size_t)(((istrip * 2 + dc) << 9) + ((4 * g + r) + 16 * gp) * 8 + eo);
      qf[a] = f2bf(aq[m][r] + bQ[o] + pe4[r]);
      kf[a] = f2bf(ak[m][r] + bK[o] + pe4[r]);
    }
  }
  // V fragment writes: c = 64wid+16m+4g+r (row idx), pos = n0+16n+l15 (col k)
  u16* vf = Vc + (size_t)b * 1048576;
  int jchunk = n0 >> 5;
#pragma unroll
  for (int m = 0; m < 4; ++m) {
    int cstrip = 4 * wid + m;
#pragma unroll
    for (int r = 0; r < 4; ++r) {
      int c15 = 4 * g + r;
      float bvv = bV[64 * wid + 16 * m + c15];
#pragma unroll
      for (int n = 0; n < 2; ++n) {
        size_t a = (size_t)(((cstrip * 128 + jchunk) << 9) +
                            (c15 + 16 * (2 * n + (l15 >> 3))) * 8 + (l15 & 7));
        vf[a] = f2bf(av[m][n][r] + bvv);
      }
    }
  }
}

// ---- pass 1: column sums + fold 1/colsum into Vf, 512 thr, grid 256 -------
__global__ __launch_bounds__(512) void k_colsum(const u16* __restrict__ Qt,
                                                const u16* __restrict__ Kt,
                                                u16* __restrict__ Vc) {
  __shared__ float ps[8][16];
  __shared__ float rsf[64];
  int b = blockIdx.x & 3, j0 = (blockIdx.x >> 2) * 64;
  int lane = threadIdx.x & 63, wid = threadIdx.x >> 6;  // wid in [0,8)
  int l15 = lane & 15, g = lane >> 4;
  int w4 = wid & 3, ihalf = wid >> 2;
  const u16* qf = Qt + (size_t)b * 262144;
  const u16* kf = Kt + (size_t)b * 262144;
  int jstrip = (j0 >> 4) + w4;
  bf16x8 fk[2];
#pragma unroll
  for (int h = 0; h < 2; ++h)
    fk[h] = ld8(kf + ((jstrip * 2 + h) << 9) + lane * 8);
  float part = 0.f;
  for (int i0 = ihalf * 2048; i0 < ihalf * 2048 + 2048; i0 += 64) {
    f32x4 acc[4];
#pragma unroll
    for (int m = 0; m < 4; ++m) acc[m] = fz4();
#pragma unroll
    for (int m = 0; m < 4; ++m) {
      int ib = ((i0 >> 4) + m) * 2;
      acc[m] = MFMA16(ld8(qf + (ib << 9) + lane * 8), fk[0], acc[m]);
      acc[m] = MFMA16(ld8(qf + ((ib + 1) << 9) + lane * 8), fk[1], acc[m]);
    }
#pragma unroll
    for (int m = 0; m < 4; ++m)
#pragma unroll
      for (int r = 0; r < 4; ++r) part += __expf(acc[m][r] * 0.125f);
  }
  part += __shfl_xor(part, 16);
  part += __shfl_xor(part, 32);
  if (g == 0) ps[wid][l15] = part;
  __syncthreads();
  if (threadIdx.x < 64) {
    int jj = threadIdx.x;
    rsf[jj] = 1.0f / (ps[jj >> 4][jj & 15] + ps[(jj >> 4) + 4][jj & 15]);
  }
  __syncthreads();
  // scale Vf for j in [j0, j0+64), all 256 channels (2 threads / channel)
  {
    int c = threadIdx.x >> 1, half = threadIdx.x & 1;
    int cstrip = c >> 4, c15 = c & 15;
    u16* vb2 = Vc + (size_t)b * 1048576;
#pragma unroll
    for (int q = 0; q < 2; ++q) {
      int jo = half * 32 + q * 16;
#pragma unroll
      for (int s = 0; s < 2; ++s) {
        int joo = jo + s * 8;
        int jc = (j0 + joo) >> 5;
        int jg = (joo & 31) >> 3;
        u16* p = vb2 + (((size_t)(cstrip * 128 + jc)) << 9) + (c15 + 16 * jg) * 8;
        ushort8 v = *reinterpret_cast<const ushort8*>(p);
        ushort8 ov;
#pragma unroll
        for (int e = 0; e < 8; ++e) ov[e] = f2bf(bf2f(v[e]) * rsf[joo + e]);
        *reinterpret_cast<ushort8*>(p) = ov;
      }
    }
  }
}

// ---- pass 2: attention + fused MLP, 1024 thr, grid 256 (b = id&3) ---------
__global__ __launch_bounds__(1024, 4) void k_attn(
    const u16* __restrict__ Qt, const u16* __restrict__ Kt,
    const u16* __restrict__ Vc, const u16* __restrict__ w1,
    const float* __restrict__ b1, const u16* __restrict__ w2,
    const float* __restrict__ b2, const float* __restrict__ x,
    float* __restrict__ out) {
  __shared__ u16 P[2][64][264];  // dbuf; reused as att/hdn tiles for MLP
  int b = blockIdx.x & 3, i0 = (blockIdx.x >> 2) * 64;
  int lane = threadIdx.x & 63, wid = threadIdx.x >> 6;  // wid in [0,16)
  int l15 = lane & 15, g = lane >> 4;
  int ih = wid >> 3, cw = wid & 7;  // PV tile: i-half, 32-c strip
  const u16* qf = Qt + (size_t)b * 262144;
  const u16* kf = Kt + (size_t)b * 262144;
  const u16* vf = Vc + (size_t)b * 1048576;

  bf16x8 aq[4][2];
#pragma unroll
  for (int m = 0; m < 4; ++m)
#pragma unroll
    for (int h = 0; h < 2; ++h)
      aq[m][h] = ld8(qf + ((((i0 >> 4) + m) * 2 + h) << 9) + lane * 8);

  f32x4 oacc[2][2];  // [m][cs]: i = i0+32ih+16m+4g+r, c = 32cw+16cs+l15
#pragma unroll
  for (int m = 0; m < 2; ++m)
#pragma unroll
    for (int cs = 0; cs < 2; ++cs) oacc[m][cs] = fz4();

  const u16* kl = kf + lane * 8;
  bf16x8 fk0 = ld8(kl + ((wid * 2 + 0) << 9));
  bf16x8 fk1 = ld8(kl + ((wid * 2 + 1) << 9));

  auto S_phase = [&](int j0, int sbuf) {
    f32x4 s[4];
#pragma unroll
    for (int m = 0; m < 4; ++m) {
      s[m] = fz4();
      s[m] = MFMA16(fk0, aq[m][0], s[m]);
      s[m] = MFMA16(fk1, aq[m][1], s[m]);
    }
#pragma unroll
    for (int m = 0; m < 4; ++m) {
      float e0 = __expf(s[m][0] * 0.125f);
      float e1 = __expf(s[m][1] * 0.125f);
      float e2 = __expf(s[m][2] * 0.125f);
      float e3 = __expf(s[m][3] * 0.125f);
      uint2v w = {cvtpk(e0, e1), cvtpk(e2, e3)};
      *reinterpret_cast<uint2v*>(&P[sbuf][16 * m + l15][16 * wid + 4 * g]) = w;
    }
    if (j0 < 3840) {
      int jstrip = ((j0 + 256) >> 4) + wid;
      fk0 = ld8(kl + ((jstrip * 2 + 0) << 9));
      fk1 = ld8(kl + ((jstrip * 2 + 1) << 9));
    }
  };
  auto PV_phase = [&](int j0, int pbuf, const bf16x8 (&fvp)[2][4]) {
    __builtin_amdgcn_s_setprio(1);
#pragma unroll
    for (int h = 0; h < 8; ++h) {
      bf16x8 ap[2];
#pragma unroll
      for (int m = 0; m < 2; ++m)
        ap[m] = ld8(&P[pbuf][32 * ih + 16 * m + l15][h * 32 + 8 * g]);
      bf16x8 f0, f1;
      if (h < 4) {
        f0 = fvp[0][h];
        f1 = fvp[1][h];
      } else {
        f0 = ld8(vf + (((2 * cw + 0) * 128 + (j0 >> 5) + h) << 9) + lane * 8);
        f1 = ld8(vf + (((2 * cw + 1) * 128 + (j0 >> 5) + h) << 9) + lane * 8);
      }
      oacc[0][0] = MFMA16(ap[0], f0, oacc[0][0]);
      oacc[0][1] = MFMA16(ap[0], f1, oacc[0][1]);
      oacc[1][0] = MFMA16(ap[1], f0, oacc[1][0]);
      oacc[1][1] = MFMA16(ap[1], f1, oacc[1][1]);
    }
    __builtin_amdgcn_s_setprio(0);
  };

  S_phase(0, 0);
  int buf = 0;
  for (int t = 0; t < 16; ++t) {
    __syncthreads();
    int j0 = t * 256;
    bf16x8 fvp[2][4];
#pragma unroll
    for (int cs = 0; cs < 2; ++cs)
#pragma unroll
      for (int h = 0; h < 4; ++h)
        fvp[cs][h] = ld8(vf + (((2 * cw + cs) * 128 + (j0 >> 5) + h) << 9) + lane * 8);
    if (wid & 1) {
      if (t < 15) S_phase(j0 + 256, buf ^ 1);
      PV_phase(j0, buf, fvp);
    } else {
      PV_phase(j0, buf, fvp);
      if (t < 15) S_phase(j0 + 256, buf ^ 1);
    }
    buf ^= 1;
  }

  // ---- fused MLP on the block's 64x256 tile ----
  u16 (*attL)[264] = P[0];  // att tile (P dead after j-loop)
  u16 (*hdnL)[264] = P[1];  // hdn tile
  __syncthreads();  // all PV reads of P complete
#pragma unroll
  for (int m = 0; m < 2; ++m)
#pragma unroll
    for (int cs = 0; cs < 2; ++cs)
#pragma unroll
      for (int r = 0; r < 4; ++r)
        attL[32 * ih + 16 * m + 4 * g + r][32 * cw + 16 * cs + l15] =
            f2bf(oacc[m][cs][r]);
  __syncthreads();

  // stage 1: hdn = mish(att @ W1^T + b1); wave strip = 16 h (ostrip = wid)
  {
    f32x4 acc1[4];
#pragma unroll
    for (int m = 0; m < 4; ++m) acc1[m] = fz4();
    for (int kk = 0; kk < 8; ++kk) {
      bf16x8 bn = ld8(w1 + ((wid * 8 + kk) << 9) + lane * 8);
#pragma unroll
      for (int m = 0; m < 4; ++m) {
        bf16x8 am = ld8(&attL[16 * m + l15][kk * 32 + 8 * g]);
        acc1[m] = MFMA16(am, bn, acc1[m]);
      }
    }
    float bb = b1[16 * wid + l15];
#pragma unroll
    for (int m = 0; m < 4; ++m)
#pragma unroll
      for (int r = 0; r < 4; ++r) {
        float v = acc1[m][r] + bb;
        float sp = (v > 15.f) ? v : __logf(1.f + __expf(v));
        float e2 = __expf(-2.f * sp);
        float th = (1.f - e2) / (1.f + e2);
        hdnL[16 * m + 4 * g + r][16 * wid + l15] = f2bf(v * th);
      }
  }
  __syncthreads();

  // stage 2: out = hdn @ W2^T + b2 + x; wave strip = 16 o (ostrip = wid)
  {
    f32x4 acc2[4];
#pragma unroll
    for (int n = 0; n < 4; ++n) acc2[n] = fz4();
    for (int kk = 0; kk < 8; ++kk) {
      bf16x8 am = ld8(w2 + ((wid * 8 + kk) << 9) + lane * 8);
#pragma unroll
      for (int n = 0; n < 4; ++n) {
        bf16x8 bn = ld8(&hdnL[16 * n + l15][kk * 32 + 8 * g]);
        acc2[n] = MFMA16(am, bn, acc2[n]);
      }
    }
    f32x4 b2v = *reinterpret_cast<const f32x4*>(b2 + 16 * wid + 4 * g);
#pragma unroll
    for (int r = 0; r < 4; ++r) {
      int o = 16 * wid + 4 * g + r;
#pragma unroll
      for (int n = 0; n < 4; ++n) {
        int pos = i0 + 16 * n + l15;
        size_t idx = ((size_t)b * 256 + o) * 4096 + pos;
        out[idx] = acc2[n][r] + b2v[r] + x[idx];
      }
    }
  }
}

// ---- workspace layout (bytes) ---------------------------------------------
#define WS_XT 0u          //  8,388,608  xTf  [4][256*8][64][8] bf16
#define WS_QT 8388608u    //  2,097,152  Qf  [4][256*2][64][8] bf16
#define WS_KT 10485760u   //  2,097,152  Kf  [4][256*2][64][8] bf16
#define WS_VC 12582912u   //  8,388,608  Vf  [4][16*128][64][8] bf16
#define WS_WQ 21037056u   //     32,768  wqf [4*8][64][8]
#define WS_WK 21069824u   //     32,768
#define WS_WV 21102592u   //    131,072  wvf [16*8][64][8]
#define WS_W1 21233664u   //    131,072
#define WS_W2 21364736u   //    131,072   (end: 21,495,808 < 29,884,416)

extern "C" void kernel_launch(void* const* d_in, const int* in_sizes, int n_in,
                              void* d_out, int out_size, void* d_ws, size_t ws_size,
                              hipStream_t stream) {
  (void)in_sizes; (void)n_in; (void)out_size; (void)ws_size;
  const float* x  = (const float*)d_in[0];
  const float* WQ = (const float*)d_in[1];
  const float* bQ = (const float*)d_in[2];
  const float* WK = (const float*)d_in[3];
  const float* bK = (const float*)d_in[4];
  const float* WV = (const float*)d_in[5];
  const float* bV = (const float*)d_in[6];
  const float* PE = (const float*)d_in[7];
  const float* W1 = (const float*)d_in[8];
  const float* b1 = (const float*)d_in[9];
  const float* W2 = (const float*)d_in[10];
  const float* b2 = (const float*)d_in[11];
  float* out = (float*)d_out;
  char* ws = (char*)d_ws;

  u16* xT   = (u16*)(ws + WS_XT);
  u16* Qt   = (u16*)(ws + WS_QT);
  u16* Kt   = (u16*)(ws + WS_KT);
  u16* Vc   = (u16*)(ws + WS_VC);
  u16* wqB  = (u16*)(ws + WS_WQ);
  u16* wkB  = (u16*)(ws + WS_WK);
  u16* wvB  = (u16*)(ws + WS_WV);
  u16* w1B  = (u16*)(ws + WS_W1);
  u16* w2B  = (u16*)(ws + WS_W2);

  k_prep<<<1136, 256, 0, stream>>>(x, WQ, WK, WV, W1, W2, xT, wqB, wkB, wvB, w1B, w2B);
  k_proj<<<512, 256, 0, stream>>>(xT, wqB, wkB, wvB, bQ, bK, bV, PE, Qt, Kt, Vc);
  k_colsum<<<256, 512, 0, stream>>>(Qt, Kt, Vc);
  k_attn<<<256, 1024, 0, stream>>>(Qt, Kt, Vc, w1B, b1, w2B, b2, x, out);
}

// Round 20
// 193.893 us; speedup vs baseline: 1.3407x; 1.0183x over previous
//
#include <hip/hip_runtime.h>

// ---------------------------------------------------------------------------
// AttentionHead: B=4, C=256, N=4096, QK=64. Column-softmax attention.
// R32 = R28/R31 + k_proj epilogue de-scatter (R19's confirmed TA-line
// mechanism applied to the LAST untouched scatter):
//  - Q/K: aq = MFMA16(fq, xa) (swapped) -> reg walks consecutive o ->
//    Qf/Kf writes become ushort4 8B stores (was 8 scalar u16 @16B stride).
//  - V: av = MFMA16(xa, fv) (swapped) -> reg walks consecutive j ->
//    Vf writes become ushort4 (was 32 scalar u16). 48 -> 12 stores/thread.
//  - Identical products + accumulate order -> bit-identical Qf/Kf/Vf
//    (layout function verified equal); consumers unchanged.
//  - PE pre-converted to frag-major f32 (PEf, 1MB) in k_prep (+128 blocks)
//    so pe reads stay float4; bQ/bK read as float4.
// k_colsum / k_attn byte-identical to R28/R31 (the 196.2us anchor).
// ---------------------------------------------------------------------------

typedef unsigned short u16;
typedef __attribute__((ext_vector_type(8))) unsigned short ushort8;
typedef __attribute__((ext_vector_type(4))) unsigned short ushort4v;
typedef __attribute__((ext_vector_type(2))) unsigned int uint2v;
typedef __attribute__((ext_vector_type(8))) __bf16 bf16x8;
typedef __attribute__((ext_vector_type(4))) float f32x4;

#define MFMA16(a, b, c) __builtin_amdgcn_mfma_f32_16x16x32_bf16((a), (b), (c), 0, 0, 0)

__device__ __forceinline__ u16 f2bf(float f) {
  unsigned int u = __builtin_bit_cast(unsigned int, f);
  u += 0x7FFFu + ((u >> 16) & 1u);  // round-to-nearest-even
  return (u16)(u >> 16);
}

__device__ __forceinline__ float bf2f(u16 v) {
  return __builtin_bit_cast(float, (unsigned int)v << 16);
}

__device__ __forceinline__ unsigned int cvtpk(float lo, float hi) {
  unsigned int r;
  asm("v_cvt_pk_bf16_f32 %0, %1, %2" : "=v"(r) : "v"(lo), "v"(hi));
  return r;
}

__device__ __forceinline__ bf16x8 ld8(const u16* p) {
  return __builtin_bit_cast(bf16x8, *reinterpret_cast<const ushort8*>(p));
}

__device__ __forceinline__ f32x4 fz4() {
  f32x4 z = {0.f, 0.f, 0.f, 0.f};
  return z;
}

// Fragment-major addressing (u16 units):
//  frag block fb = strip*NK + kchunk; addr = (fb<<9) + lane*8 + e
//  lane = idx15 + 16*g holds tensor[idx = strip*16 + idx15][k = kchunk*32 + g*8 + e]
//  Qf/Kf per batch: 256 istrips x 2 dchunks (NK=2); xTf: 256 x 8 (NK=8)
//  Vf per batch: 16 cstrips x 128 jchunks (NK=128); weights: O/16 x 8 (NK=8)
//  PEf (f32): same layout function as Qf: addr(o,pos) =
//    ((pos>>4)*2 + (o>>5))*512 + ((pos&15) + 16*((o&31)>>3))*8 + (o&7)

// ---- fused prep: transpose (0..1023) + weights (1024..1135) + PE (1136..1263)
__global__ __launch_bounds__(256) void k_prep(
    const float* __restrict__ x, const float* __restrict__ wq,
    const float* __restrict__ wk, const float* __restrict__ wv,
    const float* __restrict__ w1, const float* __restrict__ w2,
    const float* __restrict__ PE, u16* __restrict__ xT, u16* __restrict__ dq,
    u16* __restrict__ dk, u16* __restrict__ dv, u16* __restrict__ d1,
    u16* __restrict__ d2, float* __restrict__ PEf) {
  __shared__ float t[64][65];
  int id = blockIdx.x;
  if (id < 1024) {
    int n0 = (id & 63) * 64, c0 = ((id >> 6) & 3) * 64, b = id >> 8;
    int tx = threadIdx.x & 63, ty = threadIdx.x >> 6;
    const float* xb = x + ((size_t)b * 256 + c0) * 4096 + n0;
#pragma unroll
    for (int i = 0; i < 64; i += 4) t[ty + i][tx] = xb[(size_t)(ty + i) * 4096 + tx];
    __syncthreads();
    int lane = tx, w = ty;
    int l15 = lane & 15, g = lane >> 4;
    u16* xob = xT + (size_t)b * 1048576;
    int nstrip = (n0 >> 4) + w;
#pragma unroll
    for (int q = 0; q < 2; ++q) {
      int kk = (c0 >> 5) + q;
      int cl = q * 32 + g * 8;
      ushort8 v;
#pragma unroll
      for (int e = 0; e < 8; ++e) v[e] = f2bf(t[cl + e][w * 16 + l15]);
      *reinterpret_cast<ushort8*>(xob + ((size_t)(nstrip * 8 + kk) << 9) + lane * 8) = v;
    }
  } else if (id < 1136) {
    int tt = (id - 1024) * 256 + threadIdx.x;
    int lane = tt & 63, fb = tt >> 6;  // 448 frag blocks total
    const float* src;
    u16* dst;
    int base;
    if (fb < 32)       { src = wq; dst = dq; base = 0; }
    else if (fb < 64)  { src = wk; dst = dk; base = 32; }
    else if (fb < 192) { src = wv; dst = dv; base = 64; }
    else if (fb < 320) { src = w1; dst = d1; base = 192; }
    else               { src = w2; dst = d2; base = 320; }
    int lfb = fb - base;
    int ostrip = lfb >> 3, kk = lfb & 7;
    int l15 = lane & 15, g = lane >> 4;
    const float* s = src + (ostrip * 16 + l15) * 256 + kk * 32 + g * 8;
    f32x4 a0 = *reinterpret_cast<const f32x4*>(s);
    f32x4 a1 = *reinterpret_cast<const f32x4*>(s + 4);
    ushort8 v;
#pragma unroll
    for (int e = 0; e < 4; ++e) { v[e] = f2bf(a0[e]); v[4 + e] = f2bf(a1[e]); }
    *reinterpret_cast<ushort8*>(dst + ((size_t)lfb << 9) + lane * 8) = v;
  } else {
    // PE -> PEf (f32 frag-major). 32768 threads x 8 pos each.
    int tt = (id - 1136) * 256 + threadIdx.x;
    int o = tt >> 9;            // 0..63
    int pos0 = (tt & 511) * 8;  // 0..4088
    f32x4 a0 = *reinterpret_cast<const f32x4*>(PE + (size_t)o * 4096 + pos0);
    f32x4 a1 = *reinterpret_cast<const f32x4*>(PE + (size_t)o * 4096 + pos0 + 4);
    int dc = o >> 5, gp = (o & 31) >> 3, eo = o & 7;
#pragma unroll
    for (int e = 0; e < 8; ++e) {
      int pos = pos0 + e;
      int istrip = pos >> 4, p15 = pos & 15;
      PEf[(size_t)(istrip * 2 + dc) * 512 + (p15 + 16 * gp) * 8 + eo] =
          (e < 4) ? a0[e] : a1[e - 4];
    }
  }
}

// ---- fused QKV projection: 32-pos tiles, grid 512 linear (b = id&3) -------
// Swapped MFMAs -> reg walks consecutive o (Q/K) / j (V) -> ushort4 stores.
__global__ __launch_bounds__(256) void k_proj(
    const u16* __restrict__ xT, const u16* __restrict__ wq,
    const u16* __restrict__ wk, const u16* __restrict__ wv,
    const float* __restrict__ bQ, const float* __restrict__ bK,
    const float* __restrict__ bV, const float* __restrict__ PEf,
    u16* __restrict__ Qt, u16* __restrict__ Kt, u16* __restrict__ Vc) {
  int b = blockIdx.x & 3, n0 = (blockIdx.x >> 2) * 32;
  int lane = threadIdx.x & 63, wid = threadIdx.x >> 6;
  int l15 = lane & 15, g = lane >> 4;
  const u16* xf = xT + (size_t)b * 1048576;

  f32x4 aq[2], ak[2], av[4][2];
#pragma unroll
  for (int m = 0; m < 2; ++m) { aq[m] = fz4(); ak[m] = fz4(); }
#pragma unroll
  for (int m = 0; m < 4; ++m)
#pragma unroll
    for (int n = 0; n < 2; ++n) av[m][n] = fz4();

  for (int kk = 0; kk < 8; ++kk) {
    bf16x8 xa[2];
#pragma unroll
    for (int m = 0; m < 2; ++m)
      xa[m] = ld8(xf + ((((n0 >> 4) + m) * 8 + kk) << 9) + lane * 8);
    bf16x8 fq = ld8(wq + ((wid * 8 + kk) << 9) + lane * 8);
    bf16x8 fk = ld8(wk + ((wid * 8 + kk) << 9) + lane * 8);
#pragma unroll
    for (int m = 0; m < 2; ++m) {
      aq[m] = MFMA16(fq, xa[m], aq[m]);   // lane=pos15, reg=o-offset 4g+r
      ak[m] = MFMA16(fk, xa[m], ak[m]);
    }
    bf16x8 fv[4];
#pragma unroll
    for (int m = 0; m < 4; ++m)
      fv[m] = ld8(wv + (((4 * wid + m) * 8 + kk) << 9) + lane * 8);
#pragma unroll
    for (int m = 0; m < 4; ++m)
#pragma unroll
      for (int n = 0; n < 2; ++n)
        av[m][n] = MFMA16(xa[n], fv[m], av[m][n]);  // lane=c15, reg=pos-off
  }

  // Q/K: o = 16*wid + 4g + r; pos = n0 + 16m + l15.
  // addr(o,pos) = ((istrip*2+dc)<<9) + (l15 + 16*gp)*8 + (eo + r)
  int dc = wid >> 1;
  int gp = ((wid & 1) << 1) | (g >> 1);  // (o&31)>>3
  int eo = 4 * (g & 1);                  // o&7 base (r adds 0..3)
  u16* qf = Qt + (size_t)b * 262144;
  u16* kf = Kt + (size_t)b * 262144;
  f32x4 bq4 = *reinterpret_cast<const f32x4*>(bQ + 16 * wid + 4 * g);
  f32x4 bk4 = *reinterpret_cast<const f32x4*>(bK + 16 * wid + 4 * g);
#pragma unroll
  for (int m = 0; m < 2; ++m) {
    int istrip = (n0 >> 4) + m;
    size_t inner = (size_t)((istrip * 2 + dc) << 9) + (l15 + 16 * gp) * 8 + eo;
    f32x4 pe4 = *reinterpret_cast<const f32x4*>(PEf + inner);
    ushort4v qv, kv;
#pragma unroll
    for (int r = 0; r < 4; ++r) {
      qv[r] = f2bf(aq[m][r] + bq4[r] + pe4[r]);
      kv[r] = f2bf(ak[m][r] + bk4[r] + pe4[r]);
    }
    *reinterpret_cast<ushort4v*>(qf + inner) = qv;
    *reinterpret_cast<ushort4v*>(kf + inner) = kv;
  }
  // V: c = (4*wid+m)*16 + l15; pos = n0 + 16n + 4g + r.
  // addr = ((cstrip*128+jchunk)<<9) + (l15 + 16*(2n+(g>>1)))*8 + 4*(g&1) + r
  u16* vf = Vc + (size_t)b * 1048576;
  int jchunk = n0 >> 5;
#pragma unroll
  for (int m = 0; m < 4; ++m) {
    int cstrip = 4 * wid + m;
    float bvv = bV[cstrip * 16 + l15];
#pragma unroll
    for (int n = 0; n < 2; ++n) {
      size_t a = (size_t)((cstrip * 128 + jchunk) << 9) +
                 (l15 + 16 * (2 * n + (g >> 1))) * 8 + 4 * (g & 1);
      ushort4v vv;
#pragma unroll
      for (int r = 0; r < 4; ++r) vv[r] = f2bf(av[m][n][r] + bvv);
      *reinterpret_cast<ushort4v*>(vf + a) = vv;
    }
  }
}

// ---- pass 1: column sums + fold 1/colsum into Vf, 512 thr, grid 256 -------
__global__ __launch_bounds__(512) void k_colsum(const u16* __restrict__ Qt,
                                                const u16* __restrict__ Kt,
                                                u16* __restrict__ Vc) {
  __shared__ float ps[8][16];
  __shared__ float rsf[64];
  int b = blockIdx.x & 3, j0 = (blockIdx.x >> 2) * 64;
  int lane = threadIdx.x & 63, wid = threadIdx.x >> 6;  // wid in [0,8)
  int l15 = lane & 15, g = lane >> 4;
  int w4 = wid & 3, ihalf = wid >> 2;
  const u16* qf = Qt + (size_t)b * 262144;
  const u16* kf = Kt + (size_t)b * 262144;
  int jstrip = (j0 >> 4) + w4;
  bf16x8 fk[2];
#pragma unroll
  for (int h = 0; h < 2; ++h)
    fk[h] = ld8(kf + ((jstrip * 2 + h) << 9) + lane * 8);
  float part = 0.f;
  for (int i0 = ihalf * 2048; i0 < ihalf * 2048 + 2048; i0 += 64) {
    f32x4 acc[4];
#pragma unroll
    for (int m = 0; m < 4; ++m) acc[m] = fz4();
#pragma unroll
    for (int m = 0; m < 4; ++m) {
      int ib = ((i0 >> 4) + m) * 2;
      acc[m] = MFMA16(ld8(qf + (ib << 9) + lane * 8), fk[0], acc[m]);
      acc[m] = MFMA16(ld8(qf + ((ib + 1) << 9) + lane * 8), fk[1], acc[m]);
    }
#pragma unroll
    for (int m = 0; m < 4; ++m)
#pragma unroll
      for (int r = 0; r < 4; ++r) part += __expf(acc[m][r] * 0.125f);
  }
  part += __shfl_xor(part, 16);
  part += __shfl_xor(part, 32);
  if (g == 0) ps[wid][l15] = part;
  __syncthreads();
  if (threadIdx.x < 64) {
    int jj = threadIdx.x;
    rsf[jj] = 1.0f / (ps[jj >> 4][jj & 15] + ps[(jj >> 4) + 4][jj & 15]);
  }
  __syncthreads();
  // scale Vf for j in [j0, j0+64), all 256 channels (2 threads / channel)
  {
    int c = threadIdx.x >> 1, half = threadIdx.x & 1;
    int cstrip = c >> 4, c15 = c & 15;
    u16* vb2 = Vc + (size_t)b * 1048576;
#pragma unroll
    for (int q = 0; q < 2; ++q) {
      int jo = half * 32 + q * 16;
#pragma unroll
      for (int s = 0; s < 2; ++s) {
        int joo = jo + s * 8;
        int jc = (j0 + joo) >> 5;
        int jg = (joo & 31) >> 3;
        u16* p = vb2 + (((size_t)(cstrip * 128 + jc)) << 9) + (c15 + 16 * jg) * 8;
        ushort8 v = *reinterpret_cast<const ushort8*>(p);
        ushort8 ov;
#pragma unroll
        for (int e = 0; e < 8; ++e) ov[e] = f2bf(bf2f(v[e]) * rsf[joo + e]);
        *reinterpret_cast<ushort8*>(p) = ov;
      }
    }
  }
}

// ---- pass 2: attention + fused MLP, 1024 thr, grid 256 (b = id&3) ---------
__global__ __launch_bounds__(1024, 4) void k_attn(
    const u16* __restrict__ Qt, const u16* __restrict__ Kt,
    const u16* __restrict__ Vc, const u16* __restrict__ w1,
    const float* __restrict__ b1, const u16* __restrict__ w2,
    const float* __restrict__ b2, const float* __restrict__ x,
    float* __restrict__ out) {
  __shared__ u16 P[2][64][264];  // dbuf; reused as att/hdn tiles for MLP
  int b = blockIdx.x & 3, i0 = (blockIdx.x >> 2) * 64;
  int lane = threadIdx.x & 63, wid = threadIdx.x >> 6;  // wid in [0,16)
  int l15 = lane & 15, g = lane >> 4;
  int ih = wid >> 3, cw = wid & 7;  // PV tile: i-half, 32-c strip
  const u16* qf = Qt + (size_t)b * 262144;
  const u16* kf = Kt + (size_t)b * 262144;
  const u16* vf = Vc + (size_t)b * 1048576;

  bf16x8 aq[4][2];
#pragma unroll
  for (int m = 0; m < 4; ++m)
#pragma unroll
    for (int h = 0; h < 2; ++h)
      aq[m][h] = ld8(qf + ((((i0 >> 4) + m) * 2 + h) << 9) + lane * 8);

  f32x4 oacc[2][2];  // [m][cs]: i = i0+32ih+16m+4g+r, c = 32cw+16cs+l15
#pragma unroll
  for (int m = 0; m < 2; ++m)
#pragma unroll
    for (int cs = 0; cs < 2; ++cs) oacc[m][cs] = fz4();

  const u16* kl = kf + lane * 8;
  bf16x8 fk0 = ld8(kl + ((wid * 2 + 0) << 9));
  bf16x8 fk1 = ld8(kl + ((wid * 2 + 1) << 9));

  auto S_phase = [&](int j0, int sbuf) {
    f32x4 s[4];
#pragma unroll
    for (int m = 0; m < 4; ++m) {
      s[m] = fz4();
      s[m] = MFMA16(fk0, aq[m][0], s[m]);
      s[m] = MFMA16(fk1, aq[m][1], s[m]);
    }
#pragma unroll
    for (int m = 0; m < 4; ++m) {
      float e0 = __expf(s[m][0] * 0.125f);
      float e1 = __expf(s[m][1] * 0.125f);
      float e2 = __expf(s[m][2] * 0.125f);
      float e3 = __expf(s[m][3] * 0.125f);
      uint2v w = {cvtpk(e0, e1), cvtpk(e2, e3)};
      *reinterpret_cast<uint2v*>(&P[sbuf][16 * m + l15][16 * wid + 4 * g]) = w;
    }
    if (j0 < 3840) {
      int jstrip = ((j0 + 256) >> 4) + wid;
      fk0 = ld8(kl + ((jstrip * 2 + 0) << 9));
      fk1 = ld8(kl + ((jstrip * 2 + 1) << 9));
    }
  };
  auto PV_phase = [&](int j0, int pbuf, const bf16x8 (&fvp)[2][4]) {
    __builtin_amdgcn_s_setprio(1);
#pragma unroll
    for (int h = 0; h < 8; ++h) {
      bf16x8 ap[2];
#pragma unroll
      for (int m = 0; m < 2; ++m)
        ap[m] = ld8(&P[pbuf][32 * ih + 16 * m + l15][h * 32 + 8 * g]);
      bf16x8 f0, f1;
      if (h < 4) {
        f0 = fvp[0][h];
        f1 = fvp[1][h];
      } else {
        f0 = ld8(vf + (((2 * cw + 0) * 128 + (j0 >> 5) + h) << 9) + lane * 8);
        f1 = ld8(vf + (((2 * cw + 1) * 128 + (j0 >> 5) + h) << 9) + lane * 8);
      }
      oacc[0][0] = MFMA16(ap[0], f0, oacc[0][0]);
      oacc[0][1] = MFMA16(ap[0], f1, oacc[0][1]);
      oacc[1][0] = MFMA16(ap[1], f0, oacc[1][0]);
      oacc[1][1] = MFMA16(ap[1], f1, oacc[1][1]);
    }
    __builtin_amdgcn_s_setprio(0);
  };

  S_phase(0, 0);
  int buf = 0;
  for (int t = 0; t < 16; ++t) {
    __syncthreads();
    int j0 = t * 256;
    bf16x8 fvp[2][4];
#pragma unroll
    for (int cs = 0; cs < 2; ++cs)
#pragma unroll
      for (int h = 0; h < 4; ++h)
        fvp[cs][h] = ld8(vf + (((2 * cw + cs) * 128 + (j0 >> 5) + h) << 9) + lane * 8);
    if (wid & 1) {
      if (t < 15) S_phase(j0 + 256, buf ^ 1);
      PV_phase(j0, buf, fvp);
    } else {
      PV_phase(j0, buf, fvp);
      if (t < 15) S_phase(j0 + 256, buf ^ 1);
    }
    buf ^= 1;
  }

  // ---- fused MLP on the block's 64x256 tile ----
  u16 (*attL)[264] = P[0];  // att tile (P dead after j-loop)
  u16 (*hdnL)[264] = P[1];  // hdn tile
  __syncthreads();  // all PV reads of P complete
#pragma unroll
  for (int m = 0; m < 2; ++m)
#pragma unroll
    for (int cs = 0; cs < 2; ++cs)
#pragma unroll
      for (int r = 0; r < 4; ++r)
        attL[32 * ih + 16 * m + 4 * g + r][32 * cw + 16 * cs + l15] =
            f2bf(oacc[m][cs][r]);
  __syncthreads();

  // stage 1: hdn = mish(att @ W1^T + b1); wave strip = 16 h (ostrip = wid)
  {
    f32x4 acc1[4];
#pragma unroll
    for (int m = 0; m < 4; ++m) acc1[m] = fz4();
    for (int kk = 0; kk < 8; ++kk) {
      bf16x8 bn = ld8(w1 + ((wid * 8 + kk) << 9) + lane * 8);
#pragma unroll
      for (int m = 0; m < 4; ++m) {
        bf16x8 am = ld8(&attL[16 * m + l15][kk * 32 + 8 * g]);
        acc1[m] = MFMA16(am, bn, acc1[m]);
      }
    }
    float bb = b1[16 * wid + l15];
#pragma unroll
    for (int m = 0; m < 4; ++m)
#pragma unroll
      for (int r = 0; r < 4; ++r) {
        float v = acc1[m][r] + bb;
        float sp = (v > 15.f) ? v : __logf(1.f + __expf(v));
        float e2 = __expf(-2.f * sp);
        float th = (1.f - e2) / (1.f + e2);
        hdnL[16 * m + 4 * g + r][16 * wid + l15] = f2bf(v * th);
      }
  }
  __syncthreads();

  // stage 2: out = hdn @ W2^T + b2 + x; wave strip = 16 o (ostrip = wid)
  {
    f32x4 acc2[4];
#pragma unroll
    for (int n = 0; n < 4; ++n) acc2[n] = fz4();
    for (int kk = 0; kk < 8; ++kk) {
      bf16x8 am = ld8(w2 + ((wid * 8 + kk) << 9) + lane * 8);
#pragma unroll
      for (int n = 0; n < 4; ++n) {
        bf16x8 bn = ld8(&hdnL[16 * n + l15][kk * 32 + 8 * g]);
        acc2[n] = MFMA16(am, bn, acc2[n]);
      }
    }
    f32x4 b2v = *reinterpret_cast<const f32x4*>(b2 + 16 * wid + 4 * g);
#pragma unroll
    for (int r = 0; r < 4; ++r) {
      int o = 16 * wid + 4 * g + r;
#pragma unroll
      for (int n = 0; n < 4; ++n) {
        int pos = i0 + 16 * n + l15;
        size_t idx = ((size_t)b * 256 + o) * 4096 + pos;
        out[idx] = acc2[n][r] + b2v[r] + x[idx];
      }
    }
  }
}

// ---- workspace layout (bytes) ---------------------------------------------
#define WS_XT 0u          //  8,388,608  xTf  [4][256*8][64][8] bf16
#define WS_QT 8388608u    //  2,097,152  Qf  [4][256*2][64][8] bf16
#define WS_KT 10485760u   //  2,097,152  Kf  [4][256*2][64][8] bf16
#define WS_VC 12582912u   //  8,388,608  Vf  [4][16*128][64][8] bf16
#define WS_WQ 21037056u   //     32,768  wqf [4*8][64][8]
#define WS_WK 21069824u   //     32,768
#define WS_WV 21102592u   //    131,072  wvf [16*8][64][8]
#define WS_W1 21233664u   //    131,072
#define WS_W2 21364736u   //    131,072
#define WS_PEF 21495808u  //  1,048,576  PEf [512][512] f32 (frag-major)
                          //  end: 22,544,384 < 29,884,416

extern "C" void kernel_launch(void* const* d_in, const int* in_sizes, int n_in,
                              void* d_out, int out_size, void* d_ws, size_t ws_size,
                              hipStream_t stream) {
  (void)in_sizes; (void)n_in; (void)out_size; (void)ws_size;
  const float* x  = (const float*)d_in[0];
  const float* WQ = (const float*)d_in[1];
  const float* bQ = (const float*)d_in[2];
  const float* WK = (const float*)d_in[3];
  const float* bK = (const float*)d_in[4];
  const float* WV = (const float*)d_in[5];
  const float* bV = (const float*)d_in[6];
  const float* PE = (const float*)d_in[7];
  const float* W1 = (const float*)d_in[8];
  const float* b1 = (const float*)d_in[9];
  const float* W2 = (const float*)d_in[10];
  const float* b2 = (const float*)d_in[11];
  float* out = (float*)d_out;
  char* ws = (char*)d_ws;

  u16* xT    = (u16*)(ws + WS_XT);
  u16* Qt    = (u16*)(ws + WS_QT);
  u16* Kt    = (u16*)(ws + WS_KT);
  u16* Vc    = (u16*)(ws + WS_VC);
  u16* wqB   = (u16*)(ws + WS_WQ);
  u16* wkB   = (u16*)(ws + WS_WK);
  u16* wvB   = (u16*)(ws + WS_WV);
  u16* w1B   = (u16*)(ws + WS_W1);
  u16* w2B   = (u16*)(ws + WS_W2);
  float* PEf = (float*)(ws + WS_PEF);

  k_prep<<<1264, 256, 0, stream>>>(x, WQ, WK, WV, W1, W2, PE, xT, wqB, wkB,
                                   wvB, w1B, w2B, PEf);
  k_proj<<<512, 256, 0, stream>>>(xT, wqB, wkB, wvB, bQ, bK, bV, PEf, Qt, Kt, Vc);
  k_colsum<<<256, 512, 0, stream>>>(Qt, Kt, Vc);
  k_attn<<<256, 1024, 0, stream>>>(Qt, Kt, Vc, w1B, b1, w2B, b2, x, out);
}

// Round 21
// 192.160 us; speedup vs baseline: 1.3528x; 1.0090x over previous
//
#include <hip/hip_runtime.h>

// ---------------------------------------------------------------------------
// AttentionHead: B=4, C=256, N=4096, QK=64. Column-softmax attention.
// R33 = R32 (193.9us best: frag-major everywhere + k_proj swapped-MFMA
// vectorized epilogue + fused MLP-in-attn) + the LAST scatter removed:
//  - PE->PEf conversion re-mapped: thread = (frag-block fb, lane). Writes
//    become 2x f32x4 into a contiguous 2KB wave window (32 fully-covered
//    lines/instr; was 8 scattered scalar stores ~64 lines/instr). Reads
//    become 8 scalars at 4 fully-covered lines/instr. Index algebra verified
//    identical to R32's PEf layout (fb=istrip*2+dc, lane=p15+16gp, e=o&7)
//    -> bit-identical PEf. Grid unchanged (1264).
// All other kernels byte-identical to R32.
// Session: 284.8 -> 193.9us via frag-major coalescing (R19, -62), stagger
// (R21, -4), MLP+prep fusion (R24, -13), pad (R17, -3), store de-scatter
// (R32, -3). Closed axes: occupancy (R16/25/29/30 - unified-RF spill wall),
// coop fusion (R27 - grid.sync ~100us), transpose-elim (R26 - neutral).
// ---------------------------------------------------------------------------

typedef unsigned short u16;
typedef __attribute__((ext_vector_type(8))) unsigned short ushort8;
typedef __attribute__((ext_vector_type(4))) unsigned short ushort4v;
typedef __attribute__((ext_vector_type(2))) unsigned int uint2v;
typedef __attribute__((ext_vector_type(8))) __bf16 bf16x8;
typedef __attribute__((ext_vector_type(4))) float f32x4;

#define MFMA16(a, b, c) __builtin_amdgcn_mfma_f32_16x16x32_bf16((a), (b), (c), 0, 0, 0)

__device__ __forceinline__ u16 f2bf(float f) {
  unsigned int u = __builtin_bit_cast(unsigned int, f);
  u += 0x7FFFu + ((u >> 16) & 1u);  // round-to-nearest-even
  return (u16)(u >> 16);
}

__device__ __forceinline__ float bf2f(u16 v) {
  return __builtin_bit_cast(float, (unsigned int)v << 16);
}

__device__ __forceinline__ unsigned int cvtpk(float lo, float hi) {
  unsigned int r;
  asm("v_cvt_pk_bf16_f32 %0, %1, %2" : "=v"(r) : "v"(lo), "v"(hi));
  return r;
}

__device__ __forceinline__ bf16x8 ld8(const u16* p) {
  return __builtin_bit_cast(bf16x8, *reinterpret_cast<const ushort8*>(p));
}

__device__ __forceinline__ f32x4 fz4() {
  f32x4 z = {0.f, 0.f, 0.f, 0.f};
  return z;
}

// Fragment-major addressing (u16 units):
//  frag block fb = strip*NK + kchunk; addr = (fb<<9) + lane*8 + e
//  lane = idx15 + 16*g holds tensor[idx = strip*16 + idx15][k = kchunk*32 + g*8 + e]
//  Qf/Kf per batch: 256 istrips x 2 dchunks (NK=2); xTf: 256 x 8 (NK=8)
//  Vf per batch: 16 cstrips x 128 jchunks (NK=128); weights: O/16 x 8 (NK=8)
//  PEf (f32): same layout function as Qf: addr(o,pos) =
//    ((pos>>4)*2 + (o>>5))*512 + ((pos&15) + 16*((o&31)>>3))*8 + (o&7)

// ---- fused prep: transpose (0..1023) + weights (1024..1135) + PE (1136..1263)
__global__ __launch_bounds__(256) void k_prep(
    const float* __restrict__ x, const float* __restrict__ wq,
    const float* __restrict__ wk, const float* __restrict__ wv,
    const float* __restrict__ w1, const float* __restrict__ w2,
    const float* __restrict__ PE, u16* __restrict__ xT, u16* __restrict__ dq,
    u16* __restrict__ dk, u16* __restrict__ dv, u16* __restrict__ d1,
    u16* __restrict__ d2, float* __restrict__ PEf) {
  __shared__ float t[64][65];
  int id = blockIdx.x;
  if (id < 1024) {
    int n0 = (id & 63) * 64, c0 = ((id >> 6) & 3) * 64, b = id >> 8;
    int tx = threadIdx.x & 63, ty = threadIdx.x >> 6;
    const float* xb = x + ((size_t)b * 256 + c0) * 4096 + n0;
#pragma unroll
    for (int i = 0; i < 64; i += 4) t[ty + i][tx] = xb[(size_t)(ty + i) * 4096 + tx];
    __syncthreads();
    int lane = tx, w = ty;
    int l15 = lane & 15, g = lane >> 4;
    u16* xob = xT + (size_t)b * 1048576;
    int nstrip = (n0 >> 4) + w;
#pragma unroll
    for (int q = 0; q < 2; ++q) {
      int kk = (c0 >> 5) + q;
      int cl = q * 32 + g * 8;
      ushort8 v;
#pragma unroll
      for (int e = 0; e < 8; ++e) v[e] = f2bf(t[cl + e][w * 16 + l15]);
      *reinterpret_cast<ushort8*>(xob + ((size_t)(nstrip * 8 + kk) << 9) + lane * 8) = v;
    }
  } else if (id < 1136) {
    int tt = (id - 1024) * 256 + threadIdx.x;
    int lane = tt & 63, fb = tt >> 6;  // 448 frag blocks total
    const float* src;
    u16* dst;
    int base;
    if (fb < 32)       { src = wq; dst = dq; base = 0; }
    else if (fb < 64)  { src = wk; dst = dk; base = 32; }
    else if (fb < 192) { src = wv; dst = dv; base = 64; }
    else if (fb < 320) { src = w1; dst = d1; base = 192; }
    else               { src = w2; dst = d2; base = 320; }
    int lfb = fb - base;
    int ostrip = lfb >> 3, kk = lfb & 7;
    int l15 = lane & 15, g = lane >> 4;
    const float* s = src + (ostrip * 16 + l15) * 256 + kk * 32 + g * 8;
    f32x4 a0 = *reinterpret_cast<const f32x4*>(s);
    f32x4 a1 = *reinterpret_cast<const f32x4*>(s + 4);
    ushort8 v;
#pragma unroll
    for (int e = 0; e < 4; ++e) { v[e] = f2bf(a0[e]); v[4 + e] = f2bf(a1[e]); }
    *reinterpret_cast<ushort8*>(dst + ((size_t)lfb << 9) + lane * 8) = v;
  } else {
    // PE -> PEf (f32 frag-major), de-scattered: thread = (fb, lane).
    // fb = istrip*2 + dc (512 total); lane = p15 + 16*gp; e = o&7.
    // Reads: 8 scalars, 4 fully-covered lines/instr across the wave.
    // Writes: 2x f32x4 into a contiguous 2KB wave window.
    int tt = (id - 1136) * 256 + threadIdx.x;  // 32768 threads
    int lane = tt & 63, fb = tt >> 6;          // fb in [0,512)
    int istrip = fb >> 1, dc = fb & 1;
    int p15 = lane & 15, gp = lane >> 4;
    int pos = istrip * 16 + p15;
    f32x4 v0, v1;
#pragma unroll
    for (int e = 0; e < 4; ++e) {
      int o = dc * 32 + gp * 8 + e;
      v0[e] = PE[(size_t)o * 4096 + pos];
    }
#pragma unroll
    for (int e = 0; e < 4; ++e) {
      int o = dc * 32 + gp * 8 + 4 + e;
      v1[e] = PE[(size_t)o * 4096 + pos];
    }
    float* dstp = PEf + (size_t)fb * 512 + lane * 8;
    *reinterpret_cast<f32x4*>(dstp) = v0;
    *reinterpret_cast<f32x4*>(dstp + 4) = v1;
  }
}

// ---- fused QKV projection: 32-pos tiles, grid 512 linear (b = id&3) -------
// Swapped MFMAs -> reg walks consecutive o (Q/K) / j (V) -> ushort4 stores.
__global__ __launch_bounds__(256) void k_proj(
    const u16* __restrict__ xT, const u16* __restrict__ wq,
    const u16* __restrict__ wk, const u16* __restrict__ wv,
    const float* __restrict__ bQ, const float* __restrict__ bK,
    const float* __restrict__ bV, const float* __restrict__ PEf,
    u16* __restrict__ Qt, u16* __restrict__ Kt, u16* __restrict__ Vc) {
  int b = blockIdx.x & 3, n0 = (blockIdx.x >> 2) * 32;
  int lane = threadIdx.x & 63, wid = threadIdx.x >> 6;
  int l15 = lane & 15, g = lane >> 4;
  const u16* xf = xT + (size_t)b * 1048576;

  f32x4 aq[2], ak[2], av[4][2];
#pragma unroll
  for (int m = 0; m < 2; ++m) { aq[m] = fz4(); ak[m] = fz4(); }
#pragma unroll
  for (int m = 0; m < 4; ++m)
#pragma unroll
    for (int n = 0; n < 2; ++n) av[m][n] = fz4();

  for (int kk = 0; kk < 8; ++kk) {
    bf16x8 xa[2];
#pragma unroll
    for (int m = 0; m < 2; ++m)
      xa[m] = ld8(xf + ((((n0 >> 4) + m) * 8 + kk) << 9) + lane * 8);
    bf16x8 fq = ld8(wq + ((wid * 8 + kk) << 9) + lane * 8);
    bf16x8 fk = ld8(wk + ((wid * 8 + kk) << 9) + lane * 8);
#pragma unroll
    for (int m = 0; m < 2; ++m) {
      aq[m] = MFMA16(fq, xa[m], aq[m]);   // lane=pos15, reg=o-offset 4g+r
      ak[m] = MFMA16(fk, xa[m], ak[m]);
    }
    bf16x8 fv[4];
#pragma unroll
    for (int m = 0; m < 4; ++m)
      fv[m] = ld8(wv + (((4 * wid + m) * 8 + kk) << 9) + lane * 8);
#pragma unroll
    for (int m = 0; m < 4; ++m)
#pragma unroll
      for (int n = 0; n < 2; ++n)
        av[m][n] = MFMA16(xa[n], fv[m], av[m][n]);  // lane=c15, reg=pos-off
  }

  // Q/K: o = 16*wid + 4g + r; pos = n0 + 16m + l15.
  // addr(o,pos) = ((istrip*2+dc)<<9) + (l15 + 16*gp)*8 + (eo + r)
  int dc = wid >> 1;
  int gp = ((wid & 1) << 1) | (g >> 1);  // (o&31)>>3
  int eo = 4 * (g & 1);                  // o&7 base (r adds 0..3)
  u16* qf = Qt + (size_t)b * 262144;
  u16* kf = Kt + (size_t)b * 262144;
  f32x4 bq4 = *reinterpret_cast<const f32x4*>(bQ + 16 * wid + 4 * g);
  f32x4 bk4 = *reinterpret_cast<const f32x4*>(bK + 16 * wid + 4 * g);
#pragma unroll
  for (int m = 0; m < 2; ++m) {
    int istrip = (n0 >> 4) + m;
    size_t inner = (size_t)((istrip * 2 + dc) << 9) + (l15 + 16 * gp) * 8 + eo;
    f32x4 pe4 = *reinterpret_cast<const f32x4*>(PEf + inner);
    ushort4v qv, kv;
#pragma unroll
    for (int r = 0; r < 4; ++r) {
      qv[r] = f2bf(aq[m][r] + bq4[r] + pe4[r]);
      kv[r] = f2bf(ak[m][r] + bk4[r] + pe4[r]);
    }
    *reinterpret_cast<ushort4v*>(qf + inner) = qv;
    *reinterpret_cast<ushort4v*>(kf + inner) = kv;
  }
  // V: c = (4*wid+m)*16 + l15; pos = n0 + 16n + 4g + r.
  // addr = ((cstrip*128+jchunk)<<9) + (l15 + 16*(2n+(g>>1)))*8 + 4*(g&1) + r
  u16* vf = Vc + (size_t)b * 1048576;
  int jchunk = n0 >> 5;
#pragma unroll
  for (int m = 0; m < 4; ++m) {
    int cstrip = 4 * wid + m;
    float bvv = bV[cstrip * 16 + l15];
#pragma unroll
    for (int n = 0; n < 2; ++n) {
      size_t a = (size_t)((cstrip * 128 + jchunk) << 9) +
                 (l15 + 16 * (2 * n + (g >> 1))) * 8 + 4 * (g & 1);
      ushort4v vv;
#pragma unroll
      for (int r = 0; r < 4; ++r) vv[r] = f2bf(av[m][n][r] + bvv);
      *reinterpret_cast<ushort4v*>(vf + a) = vv;
    }
  }
}

// ---- pass 1: column sums + fold 1/colsum into Vf, 512 thr, grid 256 -------
__global__ __launch_bounds__(512) void k_colsum(const u16* __restrict__ Qt,
                                                const u16* __restrict__ Kt,
                                                u16* __restrict__ Vc) {
  __shared__ float ps[8][16];
  __shared__ float rsf[64];
  int b = blockIdx.x & 3, j0 = (blockIdx.x >> 2) * 64;
  int lane = threadIdx.x & 63, wid = threadIdx.x >> 6;  // wid in [0,8)
  int l15 = lane & 15, g = lane >> 4;
  int w4 = wid & 3, ihalf = wid >> 2;
  const u16* qf = Qt + (size_t)b * 262144;
  const u16* kf = Kt + (size_t)b * 262144;
  int jstrip = (j0 >> 4) + w4;
  bf16x8 fk[2];
#pragma unroll
  for (int h = 0; h < 2; ++h)
    fk[h] = ld8(kf + ((jstrip * 2 + h) << 9) + lane * 8);
  float part = 0.f;
  for (int i0 = ihalf * 2048; i0 < ihalf * 2048 + 2048; i0 += 64) {
    f32x4 acc[4];
#pragma unroll
    for (int m = 0; m < 4; ++m) acc[m] = fz4();
#pragma unroll
    for (int m = 0; m < 4; ++m) {
      int ib = ((i0 >> 4) + m) * 2;
      acc[m] = MFMA16(ld8(qf + (ib << 9) + lane * 8), fk[0], acc[m]);
      acc[m] = MFMA16(ld8(qf + ((ib + 1) << 9) + lane * 8), fk[1], acc[m]);
    }
#pragma unroll
    for (int m = 0; m < 4; ++m)
#pragma unroll
      for (int r = 0; r < 4; ++r) part += __expf(acc[m][r] * 0.125f);
  }
  part += __shfl_xor(part, 16);
  part += __shfl_xor(part, 32);
  if (g == 0) ps[wid][l15] = part;
  __syncthreads();
  if (threadIdx.x < 64) {
    int jj = threadIdx.x;
    rsf[jj] = 1.0f / (ps[jj >> 4][jj & 15] + ps[(jj >> 4) + 4][jj & 15]);
  }
  __syncthreads();
  // scale Vf for j in [j0, j0+64), all 256 channels (2 threads / channel)
  {
    int c = threadIdx.x >> 1, half = threadIdx.x & 1;
    int cstrip = c >> 4, c15 = c & 15;
    u16* vb2 = Vc + (size_t)b * 1048576;
#pragma unroll
    for (int q = 0; q < 2; ++q) {
      int jo = half * 32 + q * 16;
#pragma unroll
      for (int s = 0; s < 2; ++s) {
        int joo = jo + s * 8;
        int jc = (j0 + joo) >> 5;
        int jg = (joo & 31) >> 3;
        u16* p = vb2 + (((size_t)(cstrip * 128 + jc)) << 9) + (c15 + 16 * jg) * 8;
        ushort8 v = *reinterpret_cast<const ushort8*>(p);
        ushort8 ov;
#pragma unroll
        for (int e = 0; e < 8; ++e) ov[e] = f2bf(bf2f(v[e]) * rsf[joo + e]);
        *reinterpret_cast<ushort8*>(p) = ov;
      }
    }
  }
}

// ---- pass 2: attention + fused MLP, 1024 thr, grid 256 (b = id&3) ---------
__global__ __launch_bounds__(1024, 4) void k_attn(
    const u16* __restrict__ Qt, const u16* __restrict__ Kt,
    const u16* __restrict__ Vc, const u16* __restrict__ w1,
    const float* __restrict__ b1, const u16* __restrict__ w2,
    const float* __restrict__ b2, const float* __restrict__ x,
    float* __restrict__ out) {
  __shared__ u16 P[2][64][264];  // dbuf; reused as att/hdn tiles for MLP
  int b = blockIdx.x & 3, i0 = (blockIdx.x >> 2) * 64;
  int lane = threadIdx.x & 63, wid = threadIdx.x >> 6;  // wid in [0,16)
  int l15 = lane & 15, g = lane >> 4;
  int ih = wid >> 3, cw = wid & 7;  // PV tile: i-half, 32-c strip
  const u16* qf = Qt + (size_t)b * 262144;
  const u16* kf = Kt + (size_t)b * 262144;
  const u16* vf = Vc + (size_t)b * 1048576;

  bf16x8 aq[4][2];
#pragma unroll
  for (int m = 0; m < 4; ++m)
#pragma unroll
    for (int h = 0; h < 2; ++h)
      aq[m][h] = ld8(qf + ((((i0 >> 4) + m) * 2 + h) << 9) + lane * 8);

  f32x4 oacc[2][2];  // [m][cs]: i = i0+32ih+16m+4g+r, c = 32cw+16cs+l15
#pragma unroll
  for (int m = 0; m < 2; ++m)
#pragma unroll
    for (int cs = 0; cs < 2; ++cs) oacc[m][cs] = fz4();

  const u16* kl = kf + lane * 8;
  bf16x8 fk0 = ld8(kl + ((wid * 2 + 0) << 9));
  bf16x8 fk1 = ld8(kl + ((wid * 2 + 1) << 9));

  auto S_phase = [&](int j0, int sbuf) {
    f32x4 s[4];
#pragma unroll
    for (int m = 0; m < 4; ++m) {
      s[m] = fz4();
      s[m] = MFMA16(fk0, aq[m][0], s[m]);
      s[m] = MFMA16(fk1, aq[m][1], s[m]);
    }
#pragma unroll
    for (int m = 0; m < 4; ++m) {
      float e0 = __expf(s[m][0] * 0.125f);
      float e1 = __expf(s[m][1] * 0.125f);
      float e2 = __expf(s[m][2] * 0.125f);
      float e3 = __expf(s[m][3] * 0.125f);
      uint2v w = {cvtpk(e0, e1), cvtpk(e2, e3)};
      *reinterpret_cast<uint2v*>(&P[sbuf][16 * m + l15][16 * wid + 4 * g]) = w;
    }
    if (j0 < 3840) {
      int jstrip = ((j0 + 256) >> 4) + wid;
      fk0 = ld8(kl + ((jstrip * 2 + 0) << 9));
      fk1 = ld8(kl + ((jstrip * 2 + 1) << 9));
    }
  };
  auto PV_phase = [&](int j0, int pbuf, const bf16x8 (&fvp)[2][4]) {
    __builtin_amdgcn_s_setprio(1);
#pragma unroll
    for (int h = 0; h < 8; ++h) {
      bf16x8 ap[2];
#pragma unroll
      for (int m = 0; m < 2; ++m)
        ap[m] = ld8(&P[pbuf][32 * ih + 16 * m + l15][h * 32 + 8 * g]);
      bf16x8 f0, f1;
      if (h < 4) {
        f0 = fvp[0][h];
        f1 = fvp[1][h];
      } else {
        f0 = ld8(vf + (((2 * cw + 0) * 128 + (j0 >> 5) + h) << 9) + lane * 8);
        f1 = ld8(vf + (((2 * cw + 1) * 128 + (j0 >> 5) + h) << 9) + lane * 8);
      }
      oacc[0][0] = MFMA16(ap[0], f0, oacc[0][0]);
      oacc[0][1] = MFMA16(ap[0], f1, oacc[0][1]);
      oacc[1][0] = MFMA16(ap[1], f0, oacc[1][0]);
      oacc[1][1] = MFMA16(ap[1], f1, oacc[1][1]);
    }
    __builtin_amdgcn_s_setprio(0);
  };

  S_phase(0, 0);
  int buf = 0;
  for (int t = 0; t < 16; ++t) {
    __syncthreads();
    int j0 = t * 256;
    bf16x8 fvp[2][4];
#pragma unroll
    for (int cs = 0; cs < 2; ++cs)
#pragma unroll
      for (int h = 0; h < 4; ++h)
        fvp[cs][h] = ld8(vf + (((2 * cw + cs) * 128 + (j0 >> 5) + h) << 9) + lane * 8);
    if (wid & 1) {
      if (t < 15) S_phase(j0 + 256, buf ^ 1);
      PV_phase(j0, buf, fvp);
    } else {
      PV_phase(j0, buf, fvp);
      if (t < 15) S_phase(j0 + 256, buf ^ 1);
    }
    buf ^= 1;
  }

  // ---- fused MLP on the block's 64x256 tile ----
  u16 (*attL)[264] = P[0];  // att tile (P dead after j-loop)
  u16 (*hdnL)[264] = P[1];  // hdn tile
  __syncthreads();  // all PV reads of P complete
#pragma unroll
  for (int m = 0; m < 2; ++m)
#pragma unroll
    for (int cs = 0; cs < 2; ++cs)
#pragma unroll
      for (int r = 0; r < 4; ++r)
        attL[32 * ih + 16 * m + 4 * g + r][32 * cw + 16 * cs + l15] =
            f2bf(oacc[m][cs][r]);
  __syncthreads();

  // stage 1: hdn = mish(att @ W1^T + b1); wave strip = 16 h (ostrip = wid)
  {
    f32x4 acc1[4];
#pragma unroll
    for (int m = 0; m < 4; ++m) acc1[m] = fz4();
    for (int kk = 0; kk < 8; ++kk) {
      bf16x8 bn = ld8(w1 + ((wid * 8 + kk) << 9) + lane * 8);
#pragma unroll
      for (int m = 0; m < 4; ++m) {
        bf16x8 am = ld8(&attL[16 * m + l15][kk * 32 + 8 * g]);
        acc1[m] = MFMA16(am, bn, acc1[m]);
      }
    }
    float bb = b1[16 * wid + l15];
#pragma unroll
    for (int m = 0; m < 4; ++m)
#pragma unroll
      for (int r = 0; r < 4; ++r) {
        float v = acc1[m][r] + bb;
        float sp = (v > 15.f) ? v : __logf(1.f + __expf(v));
        float e2 = __expf(-2.f * sp);
        float th = (1.f - e2) / (1.f + e2);
        hdnL[16 * m + 4 * g + r][16 * wid + l15] = f2bf(v * th);
      }
  }
  __syncthreads();

  // stage 2: out = hdn @ W2^T + b2 + x; wave strip = 16 o (ostrip = wid)
  {
    f32x4 acc2[4];
#pragma unroll
    for (int n = 0; n < 4; ++n) acc2[n] = fz4();
    for (int kk = 0; kk < 8; ++kk) {
      bf16x8 am = ld8(w2 + ((wid * 8 + kk) << 9) + lane * 8);
#pragma unroll
      for (int n = 0; n < 4; ++n) {
        bf16x8 bn = ld8(&hdnL[16 * n + l15][kk * 32 + 8 * g]);
        acc2[n] = MFMA16(am, bn, acc2[n]);
      }
    }
    f32x4 b2v = *reinterpret_cast<const f32x4*>(b2 + 16 * wid + 4 * g);
#pragma unroll
    for (int r = 0; r < 4; ++r) {
      int o = 16 * wid + 4 * g + r;
#pragma unroll
      for (int n = 0; n < 4; ++n) {
        int pos = i0 + 16 * n + l15;
        size_t idx = ((size_t)b * 256 + o) * 4096 + pos;
        out[idx] = acc2[n][r] + b2v[r] + x[idx];
      }
    }
  }
}

// ---- workspace layout (bytes) ---------------------------------------------
#define WS_XT 0u          //  8,388,608  xTf  [4][256*8][64][8] bf16
#define WS_QT 8388608u    //  2,097,152  Qf  [4][256*2][64][8] bf16
#define WS_KT 10485760u   //  2,097,152  Kf  [4][256*2][64][8] bf16
#define WS_VC 12582912u   //  8,388,608  Vf  [4][16*128][64][8] bf16
#define WS_WQ 21037056u   //     32,768  wqf [4*8][64][8]
#define WS_WK 21069824u   //     32,768
#define WS_WV 21102592u   //    131,072  wvf [16*8][64][8]
#define WS_W1 21233664u   //    131,072
#define WS_W2 21364736u   //    131,072
#define WS_PEF 21495808u  //  1,048,576  PEf [512][512] f32 (frag-major)
                          //  end: 22,544,384 < 29,884,416

extern "C" void kernel_launch(void* const* d_in, const int* in_sizes, int n_in,
                              void* d_out, int out_size, void* d_ws, size_t ws_size,
                              hipStream_t stream) {
  (void)in_sizes; (void)n_in; (void)out_size; (void)ws_size;
  const float* x  = (const float*)d_in[0];
  const float* WQ = (const float*)d_in[1];
  const float* bQ = (const float*)d_in[2];
  const float* WK = (const float*)d_in[3];
  const float* bK = (const float*)d_in[4];
  const float* WV = (const float*)d_in[5];
  const float* bV = (const float*)d_in[6];
  const float* PE = (const float*)d_in[7];
  const float* W1 = (const float*)d_in[8];
  const float* b1 = (const float*)d_in[9];
  const float* W2 = (const float*)d_in[10];
  const float* b2 = (const float*)d_in[11];
  float* out = (float*)d_out;
  char* ws = (char*)d_ws;

  u16* xT    = (u16*)(ws + WS_XT);
  u16* Qt    = (u16*)(ws + WS_QT);
  u16* Kt    = (u16*)(ws + WS_KT);
  u16* Vc    = (u16*)(ws + WS_VC);
  u16* wqB   = (u16*)(ws + WS_WQ);
  u16* wkB   = (u16*)(ws + WS_WK);
  u16* wvB   = (u16*)(ws + WS_WV);
  u16* w1B   = (u16*)(ws + WS_W1);
  u16* w2B   = (u16*)(ws + WS_W2);
  float* PEf = (float*)(ws + WS_PEF);

  k_prep<<<1264, 256, 0, stream>>>(x, WQ, WK, WV, W1, W2, PE, xT, wqB, wkB,
                                   wvB, w1B, w2B, PEf);
  k_proj<<<512, 256, 0, stream>>>(xT, wqB, wkB, wvB, bQ, bK, bV, PEf, Qt, Kt, Vc);
  k_colsum<<<256, 512, 0, stream>>>(Qt, Kt, Vc);
  k_attn<<<256, 1024, 0, stream>>>(Qt, Kt, Vc, w1B, b1, w2B, b2, x, out);
}